// Round 9
// baseline (354.353 us; speedup 1.0000x reference)
//
#include <hip/hip_runtime.h>

// ---------------- constants ----------------
#define BATCH 4
#define NPIL 12000
#define NPTS 32
#define NCH 9
#define NXg 432
#define NYg 496
#define OHh 248
#define OWw 216
#define HWp (OHh*OWw)          // 53568
#define CAN_STRIDE ((size_t)NYg*NXg*64)      // ushort elems (bf16 canvas)
#define X1_STRIDE  ((size_t)OHh*OWw*64)      // ushort elems (bf16 x1)
#define MASKW 8192                            // mask words per batch (padded)

typedef __bf16 bf16x8 __attribute__((ext_vector_type(8)));
typedef float  f32x4  __attribute__((ext_vector_type(4)));

__device__ __forceinline__ bf16x8 as_bf16x8(uint4 u) {
    union { uint4 u; bf16x8 b; } c; c.u = u; return c.b;
}

__device__ __forceinline__ float b2f(unsigned int u) {
    union { unsigned int i; float f; } x; x.i = (u & 0xffffu) << 16; return x.f;
}
__device__ __forceinline__ unsigned short f2b(float f) {
    union { float f; unsigned int i; } x; x.f = f;
    unsigned int r = x.i + 0x7fffu + ((x.i >> 16) & 1u);   // RNE
    return (unsigned short)(r >> 16);
}
__device__ __forceinline__ float ldin(const void* p, int i, int isbf) {
    return isbf ? b2f(((const unsigned short*)p)[i]) : ((const float*)p)[i];
}

// async global->LDS DMA, 16B per lane. LDS dest must be (wave-uniform base + lane*16);
// global source may be fully per-lane (m173 pattern: swizzle lives on the SOURCE address).
__device__ __forceinline__ void async_load16(const void* gsrc, void* ldst) {
    __builtin_amdgcn_global_load_lds(
        (const __attribute__((address_space(1))) unsigned char*)gsrc,
        (__attribute__((address_space(3))) unsigned char*)ldst, 16, 0, 0);
}

__global__ void sentinel_kernel(float* out, float val) {
    if (threadIdx.x == 0) out[0] = val;
}

// ---------------- per-tensor dtype detector (robustness; all fp32 in practice) ----------------
__device__ __forceinline__ int plaus16(unsigned short h) {
    if ((h & 0x7fffu) == 0) return 1;
    unsigned e = (h >> 7) & 0xffu;
    return (e >= 106 && e <= 132) ? 1 : 0;
}

__global__ __launch_bounds__(1024) void detect_all(
    const void* q0,  const void* q1,  const void* q2,  const void* q3,
    const void* q4,  const void* q5,  const void* q6,  const void* q7,
    const void* q8,  const void* q9,  const void* q10, const void* q11,
    const void* q12, const void* q13, const void* q14, const void* q15,
    const void* q16, const void* q17, const void* q18, const void* q19,
    const void* q20, const void* q21, int* __restrict__ flags)
{
    __shared__ int votes[22];
    const void* ptrs[22] = {q0,q1,q2,q3,q4,q5,q6,q7,q8,q9,q10,q11,
                            q12,q13,q14,q15,q16,q17,q18,q19,q20,q21};
    const int Ks[22]   = {64,64,32,32,32,32,64,32,32,32,32,64,64,64,64,64,64,3,64,7,64,2};
    const int didx[22] = {0,3,4,5,6,7,8,9,10,11,12,13,14,15,16,17,18,19,20,21,22,23};
    const int tid = threadIdx.x;
    if (tid < 22) votes[tid] = 0;
    __syncthreads();
    int off = 0;
    #pragma unroll 1
    for (int t = 0; t < 22; ++t) {
        const int K = Ks[t];
        if (tid >= off && tid < off + K) {
            unsigned w = ((const unsigned*)ptrs[t])[tid - off];
            if (plaus16((unsigned short)w) && plaus16((unsigned short)(w >> 16)))
                atomicAdd(&votes[t], 1);
        }
        off += K;
    }
    __syncthreads();
    if (tid < 22) {
        int isbf;
        if (tid == 17 || tid == 19 || tid == 21) {
            int pv = votes[17] + votes[19] + votes[21];
            isbf = (pv * 4 >= 3 * 12);
        } else {
            isbf = (votes[tid] * 4 >= 3 * Ks[tid]);
        }
        flags[didx[tid]] = isbf;
    }
}

// ---------------- weight prep (+ mask & zero-stub clearing) ----------------
__global__ __launch_bounds__(256) void prep_weights(
    const void* __restrict__ w1, const void* __restrict__ w2,
    const void* __restrict__ cls_w, const void* __restrict__ reg_w, const void* __restrict__ dir_w,
    unsigned short* __restrict__ wt1, unsigned short* __restrict__ wt2,
    unsigned short* __restrict__ whh, unsigned short* __restrict__ whl,
    unsigned int* __restrict__ mask, int mask_words,
    unsigned int* __restrict__ zbuf,
    const int* __restrict__ flags)
{
    const int f1 = flags[8], f2 = flags[13];
    int i = blockIdx.x * 256 + threadIdx.x;
    if (i < mask_words) mask[i] = 0u;
    if (i < 16) zbuf[i] = 0u;
    if (i < 64*64*9) {
        int kx = i % 3; int t = i / 3; int ky = t % 3; t /= 3; int ic = t % 64; int oc = t / 64;
        wt1[((size_t)(ky*3 + kx)*64 + oc)*64 + ic] = f2b(ldin(w1, i, f1));
    }
    if (i < 128*64*9) {
        int kx = i % 3; int t = i / 3; int ky = t % 3; t /= 3; int ic = t % 64; int oc = t / 64;
        wt2[((size_t)(ky*3 + kx)*128 + oc)*64 + ic] = f2b(ldin(w2, i, f2));
    }
    if (i < 32*128) {
        int ic = i & 127, o = i >> 7;
        float wv = 0.f;
        if (o < 6)       wv = ldin(cls_w, o*128 + ic, flags[18]);
        else if (o < 20) wv = ldin(reg_w, (o-6)*128 + ic, flags[20]);
        else if (o < 24) wv = ldin(dir_w, (o-20)*128 + ic, flags[22]);
        unsigned short hi = f2b(wv);
        whh[i] = hi;
        whl[i] = f2b(wv - b2f(hi));
    }
}

// ---------------- PFN + scatter, canvas NHWC bf16 [NY,NX,64] + occupancy mask ----------------
__global__ __launch_bounds__(256) void pfn_scatter(
    const void* __restrict__ pillars, const int* __restrict__ coords,
    const void* __restrict__ pfn_w,
    const void* __restrict__ g, const void* __restrict__ bb,
    const void* __restrict__ m, const void* __restrict__ v,
    const int* __restrict__ flags, int b0,
    unsigned int* __restrict__ mask,
    unsigned short* __restrict__ canvas)
{
    __shared__ float lds[4][NPTS*NCH];
    const int wslot = threadIdx.x >> 6;
    const int lane  = threadIdx.x & 63;
    const int p = blockIdx.x * 4 + wslot;
    const int b = b0 + blockIdx.y;
    canvas += (size_t)blockIdx.y * CAN_STRIDE;
    mask   += (size_t)blockIdx.y * MASKW;
    const size_t pg = (size_t)b * NPIL + p;

    if (flags[0]) {
        const unsigned short* src = (const unsigned short*)pillars + pg * (NPTS*NCH);
        for (int idx = lane; idx < NPTS*NCH; idx += 64) lds[wslot][idx] = b2f(src[idx]);
    } else {
        const float4* src = (const float4*)((const float*)pillars + pg * (NPTS*NCH));
        for (int idx = lane; idx < (NPTS*NCH)/4; idx += 64)
            *(float4*)&lds[wslot][idx*4] = src[idx];
    }
    float w[NCH];
    const int fW = flags[3];
    #pragma unroll
    for (int c = 0; c < NCH; ++c) w[c] = ldin(pfn_w, lane*NCH + c, fW);
    float s = ldin(g, lane, flags[4]) / sqrtf(ldin(v, lane, flags[7]) + 1e-5f);
    float t = ldin(bb, lane, flags[5]) - ldin(m, lane, flags[6]) * s;
    __syncthreads();

    float mx = 0.0f;
    #pragma unroll 4
    for (int n = 0; n < NPTS; ++n) {
        const float* r = &lds[wslot][n*NCH];
        float acc = r[0] * w[0];
        #pragma unroll
        for (int c = 1; c < NCH; ++c) acc = fmaf(r[c], w[c], acc);
        mx = fmaxf(mx, fmaxf(fmaf(acc, s, t), 0.0f));
    }
    const int cx = coords[pg*2], cy = coords[pg*2 + 1];
    if (cx + cy != 0 && cx >= 0 && cx < NXg && cy >= 0 && cy < NYg) {
        const int cell = cy*NXg + cx;
        canvas[(size_t)cell*64 + lane] = f2b(mx);
        if (lane == 0) atomicOr(&mask[cell >> 5], 1u << (cell & 31));
    }
}

// B-fragment loader for conv1 (direct from L2-resident wt1)
#define LDB1(buf, tap, ks) { \
    _Pragma("unroll") \
    for (int j_ = 0; j_ < 4; ++j_) \
        buf[j_] = *(const uint4*)&wt[((size_t)((tap)*64 + j_*16 + lr))*64 + (ks)*32 + lg*8]; \
}

// ---------------- conv1 (MFMA): canvas bf16 -> x1 bf16 [248,216,64], stride 2 ----------------
// 8-oy tile, (256,4): acc[2][4]=32 AGPR + wb 32 + af/addr ~100-110 total -> under the
// 128-reg quantization boundary -> 4 waves/SIMD (2x conv2). lin 33,792 B -> 4 blk/CU LDS ok.
// DMA staging (linear LDS dest, inverse-swizzled source, zero-stub), mask-gated.
// B direct from L2-resident wt1 with 2-phase register prefetch.
__global__ __launch_bounds__(256, 4) void conv1_mfma(
    const unsigned short* __restrict__ canvas,
    const unsigned int* __restrict__ mask,
    const unsigned short* __restrict__ wt,     // bf16 [9][64 oc][64 ic]
    const uint4* __restrict__ zbuf,
    const void* __restrict__ g, const void* __restrict__ bb,
    const void* __restrict__ m, const void* __restrict__ v,
    const int* __restrict__ flags,
    unsigned short* __restrict__ x1)
{
    __shared__ __align__(16) uint4 lin[8*33*8];    // 33,792 B
    const int tid = threadIdx.x;
    const int w = tid >> 6, l = tid & 63;
    const int lr = l & 15, lg = l >> 4;
    const int px0 = blockIdx.x * 16, oy0 = blockIdx.y * 8;
    canvas += (size_t)blockIdx.z * CAN_STRIDE;
    mask   += (size_t)blockIdx.z * MASKW;
    x1     += (size_t)blockIdx.z * X1_STRIDE;

    f32x4 acc[2][4];
    #pragma unroll
    for (int t = 0; t < 2; ++t)
        #pragma unroll
        for (int n = 0; n < 4; ++n) acc[t][n] = (f32x4){0.f,0.f,0.f,0.f};

    uint4 wbA[4], wbB[4];
    LDB1(wbA, 0, 0);

    #pragma unroll 1
    for (int ky = 0; ky < 3; ++ky) {
        __syncthreads();                       // drain readers of lin
        for (int q = tid; q < 8*33*8; q += 256) {
            int s = q & 7, t2 = q >> 3, c = t2 % 33, r = t2 / 33;
            int iy = 2*oy0 + ky - 1 + 2*r, gx = 2*px0 - 1 + c;
            const void* src = zbuf;
            if ((unsigned)iy < (unsigned)NYg && (unsigned)gx < (unsigned)NXg) {
                const int cell = iy*NXg + gx;
                if ((mask[cell >> 5] >> (cell & 31)) & 1u)
                    src = &canvas[(size_t)cell*64 + (s ^ ((c >> 1) & 7))*8];
            }
            async_load16(src, &lin[q]);
        }
        __syncthreads();                       // implicit vmcnt(0) drains the DMA
        #pragma unroll 1
        for (int kx = 0; kx < 3; ++kx) {
            const int tap = ky*3 + kx;
            const int c = 2*lr + kx;
            const int key = (c >> 1) & 7;
            // phase 0: ks=0 with wbA; prefetch ks=1 -> wbB
            LDB1(wbB, tap, 1);
            __builtin_amdgcn_s_setprio(1);
            #pragma unroll
            for (int t = 0; t < 2; ++t) {
                const int base = ((2*w + t)*33 + c)*8;
                bf16x8 a0 = as_bf16x8(lin[base + (lg ^ key)]);
                #pragma unroll
                for (int n = 0; n < 4; ++n)
                    acc[t][n] = __builtin_amdgcn_mfma_f32_16x16x32_bf16(a0, as_bf16x8(wbA[n]), acc[t][n], 0, 0, 0);
            }
            __builtin_amdgcn_s_setprio(0);
            // phase 1: ks=1 with wbB; prefetch next tap ks=0 -> wbA
            if (tap < 8) LDB1(wbA, tap + 1, 0);
            __builtin_amdgcn_s_setprio(1);
            #pragma unroll
            for (int t = 0; t < 2; ++t) {
                const int base = ((2*w + t)*33 + c)*8;
                bf16x8 a1 = as_bf16x8(lin[base + ((4 + lg) ^ key)]);
                #pragma unroll
                for (int n = 0; n < 4; ++n)
                    acc[t][n] = __builtin_amdgcn_mfma_f32_16x16x32_bf16(a1, as_bf16x8(wbB[n]), acc[t][n], 0, 0, 0);
            }
            __builtin_amdgcn_s_setprio(0);
        }
    }
    float s[4], tt[4];
    #pragma unroll
    for (int n = 0; n < 4; ++n) {
        const int oc = n*16 + lr;
        s[n]  = ldin(g, oc, flags[9]) / sqrtf(ldin(v, oc, flags[12]) + 1e-5f);
        tt[n] = ldin(bb, oc, flags[10]) - ldin(m, oc, flags[11]) * s[n];
    }
    // D: col = lr = oc, row = lg*4+r = px
    #pragma unroll
    for (int t = 0; t < 2; ++t) {
        const int oy = oy0 + 2*w + t;
        if (oy >= OHh) continue;
        #pragma unroll
        for (int r = 0; r < 4; ++r) {
            const int px = px0 + lg*4 + r;
            if (px >= OWw) continue;
            unsigned short* orow = &x1[((size_t)oy*OWw + px)*64 + lr];
            #pragma unroll
            for (int n = 0; n < 4; ++n)
                orow[n*16] = f2b(fmaxf(fmaf(acc[t][n][r], s[n], tt[n]), 0.f));
        }
    }
}

// ---------------- conv2 (MFMA) + fused heads — r8-exact (measured 104 us, no spill) ----------------
__global__ __launch_bounds__(256, 2) void conv2_mfma(
    const unsigned short* __restrict__ x1,
    const unsigned short* __restrict__ wt,     // bf16 [9][128 oc][64 ic]
    const unsigned short* __restrict__ whh,    // bf16 [32 o][128 ic] head W hi
    const unsigned short* __restrict__ whl,    // bf16 [32 o][128 ic] head W lo
    const uint4* __restrict__ zbuf,
    const void* __restrict__ g, const void* __restrict__ bb,
    const void* __restrict__ m, const void* __restrict__ v,
    const void* __restrict__ cls_b, const void* __restrict__ reg_b, const void* __restrict__ dir_b,
    const int* __restrict__ flags, int b0,
    float* __restrict__ out)
{
    __shared__ __align__(16) char smem[74240];     // lin 41,472 | lw 32,768 ; P overlays 65,536
    uint4* lin = (uint4*)smem;
    uint4 (*lw)[128*8] = (uint4 (*)[128*8])(smem + 41472);
    unsigned short* P = (unsigned short*)smem;

    const int tid = threadIdx.x;
    const int w = tid >> 6, l = tid & 63;
    const int lr = l & 15, lg = l >> 4;
    const int px0 = blockIdx.x * 16, oy0 = blockIdx.y * 16;
    const int b = b0 + blockIdx.z;
    x1 += (size_t)blockIdx.z * X1_STRIDE;

    // stage lin via DMA (zero-stub for halo OOB)
    for (int q = tid; q < 18*18*8; q += 256) {
        int s = q & 7, t2 = q >> 3, c = t2 % 18, r = t2 / 18;
        int iy = oy0 - 1 + r, gx = px0 - 1 + c;
        const void* src = zbuf;
        if ((unsigned)iy < (unsigned)OHh && (unsigned)gx < (unsigned)OWw)
            src = &x1[((size_t)(iy*OWw + gx))*64 + (s ^ (c & 7))*8];
        async_load16(src, &lin[q]);
    }
    // stage lw[0] (tap 0) via DMA
    #pragma unroll
    for (int i = 0; i < 4; ++i) {
        const int q = tid + i*256, oc = q >> 3, s = q & 7;
        async_load16(&wt[((size_t)oc)*64 + (s ^ (oc & 7))*8], &lw[0][q]);
    }
    __syncthreads();

    f32x4 acc[4][8];
    #pragma unroll
    for (int t = 0; t < 4; ++t)
        #pragma unroll
        for (int n = 0; n < 8; ++n) acc[t][n] = (f32x4){0.f,0.f,0.f,0.f};

    #pragma unroll 1
    for (int tap = 0; tap < 9; ++tap) {
        const int ky = tap / 3, kx = tap - 3*ky;
        const int cur = tap & 1;
        if (tap < 8) {                          // DMA next tap's weights into the other buffer
            #pragma unroll
            for (int i = 0; i < 4; ++i) {
                const int q = tid + i*256, oc = q >> 3, s = q & 7;
                async_load16(&wt[((size_t)((tap+1)*128 + oc))*64 + (s ^ (oc & 7))*8],
                             &lw[cur ^ 1][q]);
            }
        }
        const int c = lr + kx;
        const int key = c & 7;
        bf16x8 af[4][2];
        #pragma unroll
        for (int t = 0; t < 4; ++t) {
            const int base = ((4*w + t + ky)*18 + c)*8;
            af[t][0] = as_bf16x8(lin[base + (lg ^ key)]);
            af[t][1] = as_bf16x8(lin[base + ((4 + lg) ^ key)]);
        }
        __builtin_amdgcn_s_setprio(1);
        #pragma unroll
        for (int n = 0; n < 8; ++n) {
            const int oc = n*16 + lr;
            const bf16x8 b0 = as_bf16x8(lw[cur][oc*8 + (lg ^ (oc & 7))]);
            const bf16x8 b1 = as_bf16x8(lw[cur][oc*8 + ((4 + lg) ^ (oc & 7))]);
            #pragma unroll
            for (int t = 0; t < 4; ++t) {
                acc[t][n] = __builtin_amdgcn_mfma_f32_16x16x32_bf16(af[t][0], b0, acc[t][n], 0, 0, 0);
                acc[t][n] = __builtin_amdgcn_mfma_f32_16x16x32_bf16(af[t][1], b1, acc[t][n], 0, 0, 0);
            }
        }
        __builtin_amdgcn_s_setprio(0);
        __syncthreads();                        // drains DMA; next tap's lw ready
    }

    float s[8], tt[8];
    #pragma unroll
    for (int n = 0; n < 8; ++n) {
        const int oc = n*16 + lr;
        s[n]  = ldin(g, oc, flags[14]) / sqrtf(ldin(v, oc, flags[17]) + 1e-5f);
        tt[n] = ldin(bb, oc, flags[15]) - ldin(m, oc, flags[16]) * s[n];
    }

    // ---- fused heads (r2-exact epilogue: pre-held hi/lo weights) ----
    float bias0, bias1;
    {
        int o = lr;
        bias0 = (o < 6) ? ldin(cls_b, o, flags[19]) : ldin(reg_b, o - 6, flags[21]);
        o = 16 + lr;
        bias1 = (o < 20) ? ldin(reg_b, o - 6, flags[21])
              : (o < 24) ? ldin(dir_b, o - 20, flags[23]) : 0.f;
    }
    uint4 wh[2][4], wl[2][4];
    #pragma unroll
    for (int n = 0; n < 2; ++n)
        #pragma unroll
        for (int ks = 0; ks < 4; ++ks) {
            const int ei = (n*16 + lr)*128 + ks*32 + lg*8;
            wh[n][ks] = *(const uint4*)&whh[ei];
            wl[n][ks] = *(const uint4*)&whl[ei];
        }

    __syncthreads();            // all waves done reading lin/lw before P overlay
    #pragma unroll
    for (int t = 0; t < 4; ++t) {
        const int pb = ((4*w + t)*16 + lg*4) * 128;
        #pragma unroll
        for (int n = 0; n < 8; ++n) {
            const int kk = 2*n + (lr >> 3), wi = lr & 7;
            #pragma unroll
            for (int r = 0; r < 4; ++r) {
                float val = fmaxf(fmaf(acc[t][n][r], s[n], tt[n]), 0.f);
                unsigned short h = f2b(val);
                P[pb + r*128 + ((kk ^ (lg*4 + r)) << 3) + wi] = h;
                acc[t][n][r] = val - b2f(h);
            }
        }
    }
    __syncthreads();

    f32x4 hacc[4][2];
    #pragma unroll
    for (int t = 0; t < 4; ++t) {
        hacc[t][0] = (f32x4){bias0, bias0, bias0, bias0};
        hacc[t][1] = (f32x4){bias1, bias1, bias1, bias1};
    }
    // pass 1: hi*Whi + hi*Wlo
    #pragma unroll
    for (int t = 0; t < 4; ++t) {
        const int mt = 4*w + t;
        bf16x8 pa[4];
        #pragma unroll
        for (int ks = 0; ks < 4; ++ks)
            pa[ks] = as_bf16x8(((const uint4*)P)[(mt*16 + lr)*16 + ((ks*4 + lg) ^ lr)]);
        #pragma unroll
        for (int n = 0; n < 2; ++n)
            #pragma unroll
            for (int ks = 0; ks < 4; ++ks) {
                hacc[t][n] = __builtin_amdgcn_mfma_f32_16x16x32_bf16(pa[ks], as_bf16x8(wh[n][ks]), hacc[t][n], 0, 0, 0);
                hacc[t][n] = __builtin_amdgcn_mfma_f32_16x16x32_bf16(pa[ks], as_bf16x8(wl[n][ks]), hacc[t][n], 0, 0, 0);
            }
    }
    __syncthreads();
    // fill P with lo
    #pragma unroll
    for (int t = 0; t < 4; ++t) {
        const int pb = ((4*w + t)*16 + lg*4) * 128;
        #pragma unroll
        for (int n = 0; n < 8; ++n) {
            const int kk = 2*n + (lr >> 3), wi = lr & 7;
            #pragma unroll
            for (int r = 0; r < 4; ++r)
                P[pb + r*128 + ((kk ^ (lg*4 + r)) << 3) + wi] = f2b(acc[t][n][r]);
        }
    }
    __syncthreads();
    // pass 2: lo*Whi
    #pragma unroll
    for (int t = 0; t < 4; ++t) {
        const int mt = 4*w + t;
        bf16x8 pa[4];
        #pragma unroll
        for (int ks = 0; ks < 4; ++ks)
            pa[ks] = as_bf16x8(((const uint4*)P)[(mt*16 + lr)*16 + ((ks*4 + lg) ^ lr)]);
        #pragma unroll
        for (int n = 0; n < 2; ++n)
            #pragma unroll
            for (int ks = 0; ks < 4; ++ks)
                hacc[t][n] = __builtin_amdgcn_mfma_f32_16x16x32_bf16(pa[ks], as_bf16x8(wh[n][ks]), hacc[t][n], 0, 0, 0);
    }

    const size_t regbase = (size_t)BATCH*6*HWp;
    const size_t dirbase = regbase + (size_t)BATCH*14*HWp;
    const int pxw = px0 + lg*4;
    #pragma unroll
    for (int n = 0; n < 2; ++n) {
        const int o = n*16 + lr;
        float* plane;
        bool valid = (pxw < OWw);
        if (o < 6)       plane = out + ((size_t)b*6 + o)*HWp;
        else if (o < 20) plane = out + regbase + ((size_t)b*14 + (o - 6))*HWp;
        else if (o < 24) plane = out + dirbase + ((size_t)b*4 + (o - 20))*HWp;
        else valid = false;
        if (!valid) continue;
        #pragma unroll
        for (int t = 0; t < 4; ++t) {
            const int oy = oy0 + 4*w + t;
            if (oy < OHh)
                *(float4*)&plane[(size_t)oy*OWw + pxw] = *(float4*)&hacc[t][n];
        }
    }
}

extern "C" void kernel_launch(void* const* d_in, const int* in_sizes, int n_in,
                              void* d_out, int out_size, void* d_ws, size_t ws_size,
                              hipStream_t stream) {
    static const int EXPECT[24] = {13824000,96000,48000,576,64,64,64,64,36864,
                                   64,64,64,64,73728,128,128,128,128,768,6,1792,14,512,4};
    const void* din[24];
    {
        bool used[24] = {false};
        int perm[24];
        bool ok = (n_in >= 24);
        if (ok) {
            for (int j = 0; j < 24 && ok; ++j) {
                perm[j] = -1;
                for (int i = 0; i < 24; ++i)
                    if (!used[i] && in_sizes[i] == EXPECT[j]) { perm[j] = i; used[i] = true; break; }
                if (perm[j] < 0) ok = false;
            }
        }
        for (int j = 0; j < 24; ++j) din[j] = d_in[ok ? perm[j] : j];
        if (!ok) {
            sentinel_kernel<<<1, 64, 0, stream>>>((float*)d_out, 13000.0f + n_in);
            return;
        }
    }
    const int* coords = (const int*)din[1];
    float* out = (float*)d_out;

    // layout: flags 256 | wt1 73,728 | wt2 147,456 | whh 8,192 | whl 8,192 | zbuf 64 |
    //         mask (nb x 32,768) | x1 bf16 (nb x 6,856,704) | canvas bf16 (nb x 27,426,816)
    const size_t X1B   = (size_t)HWp*64*2;          // 6,856,704
    const size_t CANB  = (size_t)NYg*NXg*64*2;      // 27,426,816
    const size_t MASKB = (size_t)MASKW*4;           // 32,768
    const size_t ZOFF  = 256 + 73728 + 147456 + 8192 + 8192;   // 237,824
    const size_t BASE  = ZOFF + 64;                 // 237,888
    const size_t NEED1 = BASE + MASKB + X1B + CANB;
    const size_t NEED4 = BASE + 4*(MASKB + X1B + CANB);
    if (ws_size < NEED1) {
        sentinel_kernel<<<1, 64, 0, stream>>>(out, 10000.0f + (float)(ws_size >> 20));
        return;
    }
    const int nb = (ws_size >= NEED4) ? 4 : 1;
    char* ws = (char*)d_ws;
    int* flags = (int*)ws;
    unsigned short* wt1 = (unsigned short*)(ws + 256);
    unsigned short* wt2 = (unsigned short*)(ws + 256 + 73728);
    unsigned short* whh = (unsigned short*)(ws + 256 + 73728 + 147456);
    unsigned short* whl = (unsigned short*)(ws + 256 + 73728 + 147456 + 8192);
    unsigned int*   zbuf = (unsigned int*)(ws + ZOFF);
    unsigned int*   maskbuf = (unsigned int*)(ws + BASE);
    unsigned short* x1  = (unsigned short*)(ws + BASE + (size_t)nb*MASKB);
    unsigned short* canvas = (unsigned short*)(ws + BASE + (size_t)nb*(MASKB + X1B));

    detect_all<<<1, 1024, 0, stream>>>(
        din[0], din[3], din[4], din[5], din[6], din[7],
        din[8], din[9], din[10], din[11], din[12],
        din[13], din[14], din[15], din[16], din[17],
        din[18], din[19], din[20], din[21], din[22], din[23], flags);
    prep_weights<<<288, 256, 0, stream>>>(
        din[8], din[13], din[18], din[20], din[22], wt1, wt2, whh, whl,
        maskbuf, nb*MASKW, zbuf, flags);

    if (nb == 4) {
        pfn_scatter<<<dim3(NPIL/4, 4), 256, 0, stream>>>(
            din[0], coords, din[3], din[4], din[5], din[6], din[7], flags, 0, maskbuf, canvas);
        conv1_mfma<<<dim3(14, 31, 4), 256, 0, stream>>>(
            canvas, maskbuf, wt1, (const uint4*)zbuf,
            din[9], din[10], din[11], din[12], flags, x1);
        conv2_mfma<<<dim3(14, 16, 4), 256, 0, stream>>>(
            x1, wt2, whh, whl, (const uint4*)zbuf, din[14], din[15], din[16], din[17],
            din[19], din[21], din[23], flags, 0, out);
    } else {
        for (int b = 0; b < BATCH; ++b) {
            if (b) hipMemsetAsync(maskbuf, 0, MASKB, stream);   // b=0 zeroed by prep_weights
            pfn_scatter<<<dim3(NPIL/4, 1), 256, 0, stream>>>(
                din[0], coords, din[3], din[4], din[5], din[6], din[7], flags, b, maskbuf, canvas);
            conv1_mfma<<<dim3(14, 31, 1), 256, 0, stream>>>(
                canvas, maskbuf, wt1, (const uint4*)zbuf,
                din[9], din[10], din[11], din[12], flags, x1);
            conv2_mfma<<<dim3(14, 16, 1), 256, 0, stream>>>(
                x1, wt2, whh, whl, (const uint4*)zbuf, din[14], din[15], din[16], din[17],
                din[19], din[21], din[23], flags, b, out);
        }
    }
}

// Round 10
// 334.370 us; speedup vs baseline: 1.0598x; 1.0598x over previous
//
#include <hip/hip_runtime.h>

// ---------------- constants ----------------
#define BATCH 4
#define NPIL 12000
#define NPTS 32
#define NCH 9
#define NXg 432
#define NYg 496
#define OHh 248
#define OWw 216
#define HWp (OHh*OWw)          // 53568
#define CAN_STRIDE ((size_t)NYg*NXg*64)      // ushort elems (bf16 canvas)
#define X1_STRIDE  ((size_t)OHh*OWw*64)      // ushort elems (bf16 x1)
#define MASKW 8192                            // mask words per batch (padded)

typedef __bf16 bf16x8 __attribute__((ext_vector_type(8)));
typedef float  f32x4  __attribute__((ext_vector_type(4)));

__device__ __forceinline__ bf16x8 as_bf16x8(uint4 u) {
    union { uint4 u; bf16x8 b; } c; c.u = u; return c.b;
}

__device__ __forceinline__ float b2f(unsigned int u) {
    union { unsigned int i; float f; } x; x.i = (u & 0xffffu) << 16; return x.f;
}
__device__ __forceinline__ unsigned short f2b(float f) {
    union { float f; unsigned int i; } x; x.f = f;
    unsigned int r = x.i + 0x7fffu + ((x.i >> 16) & 1u);   // RNE
    return (unsigned short)(r >> 16);
}
__device__ __forceinline__ float ldin(const void* p, int i, int isbf) {
    return isbf ? b2f(((const unsigned short*)p)[i]) : ((const float*)p)[i];
}

// async global->LDS DMA, 16B per lane. LDS dest must be (wave-uniform base + lane*16);
// global source may be fully per-lane (m173 pattern: swizzle lives on the SOURCE address).
__device__ __forceinline__ void async_load16(const void* gsrc, void* ldst) {
    __builtin_amdgcn_global_load_lds(
        (const __attribute__((address_space(1))) unsigned char*)gsrc,
        (__attribute__((address_space(3))) unsigned char*)ldst, 16, 0, 0);
}

__global__ void sentinel_kernel(float* out, float val) {
    if (threadIdx.x == 0) out[0] = val;
}

// ---------------- dtype plausibility (robustness; all fp32 in practice) ----------------
__device__ __forceinline__ int plaus16(unsigned short h) {
    if ((h & 0x7fffu) == 0) return 1;
    unsigned e = (h >> 7) & 0xffu;
    return (e >= 106 && e <= 132) ? 1 : 0;
}

// ---------------- weight prep + integrated per-block dtype detection ----------------
// Replaces the serialized single-block detect_all kernel: every prep block computes the
// full 22-tensor vote locally (972 word-checks over 4 strided windows; tensor loop fully
// unrolled so ptrs[] stays in SGPRs), uses its own flags for conversion, and block 0
// publishes the flags array for the downstream kernels (stream order covers the dep).
__global__ __launch_bounds__(256) void prep_weights(
    const void* q0,  const void* q1,  const void* q2,  const void* q3,
    const void* q4,  const void* q5,  const void* q6,  const void* q7,
    const void* q8,  const void* q9,  const void* q10, const void* q11,
    const void* q12, const void* q13, const void* q14, const void* q15,
    const void* q16, const void* q17, const void* q18, const void* q19,
    const void* q20, const void* q21,
    unsigned short* __restrict__ wt1, unsigned short* __restrict__ wt2,
    unsigned short* __restrict__ whh, unsigned short* __restrict__ whl,
    unsigned int* __restrict__ mask, int mask_words,
    unsigned int* __restrict__ zbuf,
    int* __restrict__ flags_out)
{
    __shared__ int votes[22];
    __shared__ int sflags[24];
    const void* ptrs[22] = {q0,q1,q2,q3,q4,q5,q6,q7,q8,q9,q10,q11,
                            q12,q13,q14,q15,q16,q17,q18,q19,q20,q21};
    const int Ks[22]   = {64,64,32,32,32,32,64,32,32,32,32,64,64,64,64,64,64,3,64,7,64,2};
    const int didx[22] = {0,3,4,5,6,7,8,9,10,11,12,13,14,15,16,17,18,19,20,21,22,23};
    const int tid = threadIdx.x;
    if (tid < 22) votes[tid] = 0;
    if (tid < 24) sflags[tid] = 0;
    __syncthreads();
    #pragma unroll 1
    for (int wb = 0; wb < 4; ++wb) {          // 4 windows cover cumulative offset space (972)
        const int vt = wb*256 + tid;
        int off = 0;
        #pragma unroll                         // full unroll -> constant ptrs[] indices (SGPR)
        for (int t = 0; t < 22; ++t) {
            if (vt >= off && vt < off + Ks[t]) {
                unsigned w = ((const unsigned*)ptrs[t])[vt - off];
                if (plaus16((unsigned short)w) && plaus16((unsigned short)(w >> 16)))
                    atomicAdd(&votes[t], 1);
            }
            off += Ks[t];
        }
    }
    __syncthreads();
    if (tid < 22) {
        int isbf;
        if (tid == 17 || tid == 19 || tid == 21) {
            int pv = votes[17] + votes[19] + votes[21];
            isbf = (pv * 4 >= 3 * 12);
        } else {
            isbf = (votes[tid] * 4 >= 3 * Ks[tid]);
        }
        sflags[didx[tid]] = isbf;
    }
    __syncthreads();
    if (blockIdx.x == 0 && tid < 24) flags_out[tid] = sflags[tid];

    const int f1 = sflags[8], f2 = sflags[13];
    int i = blockIdx.x * 256 + tid;
    if (i < mask_words) mask[i] = 0u;
    if (i < 16) zbuf[i] = 0u;
    if (i < 64*64*9) {
        int kx = i % 3; int t = i / 3; int ky = t % 3; t /= 3; int ic = t % 64; int oc = t / 64;
        wt1[((size_t)(ky*3 + kx)*64 + oc)*64 + ic] = f2b(ldin(q6, i, f1));      // q6 = w1
    }
    if (i < 128*64*9) {
        int kx = i % 3; int t = i / 3; int ky = t % 3; t /= 3; int ic = t % 64; int oc = t / 64;
        wt2[((size_t)(ky*3 + kx)*128 + oc)*64 + ic] = f2b(ldin(q11, i, f2));    // q11 = w2
    }
    if (i < 32*128) {
        int ic = i & 127, o = i >> 7;
        float wv = 0.f;
        if (o < 6)       wv = ldin(q16, o*128 + ic, sflags[18]);                // cls_w
        else if (o < 20) wv = ldin(q18, (o-6)*128 + ic, sflags[20]);            // reg_w
        else if (o < 24) wv = ldin(q20, (o-20)*128 + ic, sflags[22]);           // dir_w
        unsigned short hi = f2b(wv);
        whh[i] = hi;
        whl[i] = f2b(wv - b2f(hi));
    }
}

// ---------------- PFN + scatter, canvas NHWC bf16 [NY,NX,64] + occupancy mask ----------------
__global__ __launch_bounds__(256) void pfn_scatter(
    const void* __restrict__ pillars, const int* __restrict__ coords,
    const void* __restrict__ pfn_w,
    const void* __restrict__ g, const void* __restrict__ bb,
    const void* __restrict__ m, const void* __restrict__ v,
    const int* __restrict__ flags, int b0,
    unsigned int* __restrict__ mask,
    unsigned short* __restrict__ canvas)
{
    __shared__ float lds[4][NPTS*NCH];
    const int wslot = threadIdx.x >> 6;
    const int lane  = threadIdx.x & 63;
    const int p = blockIdx.x * 4 + wslot;
    const int b = b0 + blockIdx.y;
    canvas += (size_t)blockIdx.y * CAN_STRIDE;
    mask   += (size_t)blockIdx.y * MASKW;
    const size_t pg = (size_t)b * NPIL + p;

    if (flags[0]) {
        const unsigned short* src = (const unsigned short*)pillars + pg * (NPTS*NCH);
        for (int idx = lane; idx < NPTS*NCH; idx += 64) lds[wslot][idx] = b2f(src[idx]);
    } else {
        const float4* src = (const float4*)((const float*)pillars + pg * (NPTS*NCH));
        for (int idx = lane; idx < (NPTS*NCH)/4; idx += 64)
            *(float4*)&lds[wslot][idx*4] = src[idx];
    }
    float w[NCH];
    const int fW = flags[3];
    #pragma unroll
    for (int c = 0; c < NCH; ++c) w[c] = ldin(pfn_w, lane*NCH + c, fW);
    float s = ldin(g, lane, flags[4]) / sqrtf(ldin(v, lane, flags[7]) + 1e-5f);
    float t = ldin(bb, lane, flags[5]) - ldin(m, lane, flags[6]) * s;
    __syncthreads();

    float mx = 0.0f;
    #pragma unroll 4
    for (int n = 0; n < NPTS; ++n) {
        const float* r = &lds[wslot][n*NCH];
        float acc = r[0] * w[0];
        #pragma unroll
        for (int c = 1; c < NCH; ++c) acc = fmaf(r[c], w[c], acc);
        mx = fmaxf(mx, fmaxf(fmaf(acc, s, t), 0.0f));
    }
    const int cx = coords[pg*2], cy = coords[pg*2 + 1];
    if (cx + cy != 0 && cx >= 0 && cx < NXg && cy >= 0 && cy < NYg) {
        const int cell = cy*NXg + cx;
        canvas[(size_t)cell*64 + lane] = f2b(mx);
        if (lane == 0) atomicOr(&mask[cell >> 5], 1u << (cell & 31));
    }
}

// B-fragment loader for conv1 (direct from L2-resident wt1)
#define LDB1(buf, tap, ks) { \
    _Pragma("unroll") \
    for (int j_ = 0; j_ < 4; ++j_) \
        buf[j_] = *(const uint4*)&wt[((size_t)((tap)*64 + j_*16 + lr))*64 + (ks)*32 + lg*8]; \
}

// ---------------- conv1 (MFMA): canvas bf16 -> x1 bf16 [248,216,64], stride 2 ----------------
// r8-exact (16-oy tile, (256,2) — the proven 339.8 config; r9's 8-oy/(256,4) regressed from
// doubled per-block fixed costs). DMA staging (linear LDS dest, inverse-swizzled source,
// zero-stub), mask-gated. B direct from wt1 with 2-phase register prefetch. LDS 67,584.
__global__ __launch_bounds__(256, 2) void conv1_mfma(
    const unsigned short* __restrict__ canvas,
    const unsigned int* __restrict__ mask,
    const unsigned short* __restrict__ wt,     // bf16 [9][64 oc][64 ic]
    const uint4* __restrict__ zbuf,
    const void* __restrict__ g, const void* __restrict__ bb,
    const void* __restrict__ m, const void* __restrict__ v,
    const int* __restrict__ flags,
    unsigned short* __restrict__ x1)
{
    __shared__ __align__(16) uint4 lin[16*33*8];   // 67,584 B
    const int tid = threadIdx.x;
    const int w = tid >> 6, l = tid & 63;
    const int lr = l & 15, lg = l >> 4;
    const int px0 = blockIdx.x * 16, oy0 = blockIdx.y * 16;
    canvas += (size_t)blockIdx.z * CAN_STRIDE;
    mask   += (size_t)blockIdx.z * MASKW;
    x1     += (size_t)blockIdx.z * X1_STRIDE;

    f32x4 acc[4][4];
    #pragma unroll
    for (int t = 0; t < 4; ++t)
        #pragma unroll
        for (int n = 0; n < 4; ++n) acc[t][n] = (f32x4){0.f,0.f,0.f,0.f};

    uint4 wbA[4], wbB[4];
    LDB1(wbA, 0, 0);

    #pragma unroll 1
    for (int ky = 0; ky < 3; ++ky) {
        __syncthreads();                       // drain readers of lin
        for (int q = tid; q < 16*33*8; q += 256) {
            int s = q & 7, t2 = q >> 3, c = t2 % 33, r = t2 / 33;
            int iy = 2*oy0 + ky - 1 + 2*r, gx = 2*px0 - 1 + c;
            const void* src = zbuf;
            if ((unsigned)iy < (unsigned)NYg && (unsigned)gx < (unsigned)NXg) {
                const int cell = iy*NXg + gx;
                if ((mask[cell >> 5] >> (cell & 31)) & 1u)
                    src = &canvas[(size_t)cell*64 + (s ^ ((c >> 1) & 7))*8];
            }
            async_load16(src, &lin[q]);
        }
        __syncthreads();                       // implicit vmcnt(0) drains the DMA
        #pragma unroll 1
        for (int kx = 0; kx < 3; ++kx) {
            const int tap = ky*3 + kx;
            const int c = 2*lr + kx;
            const int key = (c >> 1) & 7;
            // phase 0: ks=0 with wbA; prefetch ks=1 -> wbB
            LDB1(wbB, tap, 1);
            __builtin_amdgcn_s_setprio(1);
            #pragma unroll
            for (int t = 0; t < 4; ++t) {
                const int base = ((4*w + t)*33 + c)*8;
                bf16x8 a0 = as_bf16x8(lin[base + (lg ^ key)]);
                #pragma unroll
                for (int n = 0; n < 4; ++n)
                    acc[t][n] = __builtin_amdgcn_mfma_f32_16x16x32_bf16(a0, as_bf16x8(wbA[n]), acc[t][n], 0, 0, 0);
            }
            __builtin_amdgcn_s_setprio(0);
            // phase 1: ks=1 with wbB; prefetch next tap ks=0 -> wbA
            if (tap < 8) LDB1(wbA, tap + 1, 0);
            __builtin_amdgcn_s_setprio(1);
            #pragma unroll
            for (int t = 0; t < 4; ++t) {
                const int base = ((4*w + t)*33 + c)*8;
                bf16x8 a1 = as_bf16x8(lin[base + ((4 + lg) ^ key)]);
                #pragma unroll
                for (int n = 0; n < 4; ++n)
                    acc[t][n] = __builtin_amdgcn_mfma_f32_16x16x32_bf16(a1, as_bf16x8(wbB[n]), acc[t][n], 0, 0, 0);
            }
            __builtin_amdgcn_s_setprio(0);
        }
    }
    float s[4], tt[4];
    #pragma unroll
    for (int n = 0; n < 4; ++n) {
        const int oc = n*16 + lr;
        s[n]  = ldin(g, oc, flags[9]) / sqrtf(ldin(v, oc, flags[12]) + 1e-5f);
        tt[n] = ldin(bb, oc, flags[10]) - ldin(m, oc, flags[11]) * s[n];
    }
    // D: col = lr = oc, row = lg*4+r = px
    #pragma unroll
    for (int t = 0; t < 4; ++t) {
        const int oy = oy0 + 4*w + t;
        if (oy >= OHh) continue;
        #pragma unroll
        for (int r = 0; r < 4; ++r) {
            const int px = px0 + lg*4 + r;
            if (px >= OWw) continue;
            unsigned short* orow = &x1[((size_t)oy*OWw + px)*64 + lr];
            #pragma unroll
            for (int n = 0; n < 4; ++n)
                orow[n*16] = f2b(fmaxf(fmaf(acc[t][n][r], s[n], tt[n]), 0.f));
        }
    }
}

// ---------------- conv2 (MFMA) + fused heads — r8-exact (measured 104 us, no spill) ----------------
__global__ __launch_bounds__(256, 2) void conv2_mfma(
    const unsigned short* __restrict__ x1,
    const unsigned short* __restrict__ wt,     // bf16 [9][128 oc][64 ic]
    const unsigned short* __restrict__ whh,    // bf16 [32 o][128 ic] head W hi
    const unsigned short* __restrict__ whl,    // bf16 [32 o][128 ic] head W lo
    const uint4* __restrict__ zbuf,
    const void* __restrict__ g, const void* __restrict__ bb,
    const void* __restrict__ m, const void* __restrict__ v,
    const void* __restrict__ cls_b, const void* __restrict__ reg_b, const void* __restrict__ dir_b,
    const int* __restrict__ flags, int b0,
    float* __restrict__ out)
{
    __shared__ __align__(16) char smem[74240];     // lin 41,472 | lw 32,768 ; P overlays 65,536
    uint4* lin = (uint4*)smem;
    uint4 (*lw)[128*8] = (uint4 (*)[128*8])(smem + 41472);
    unsigned short* P = (unsigned short*)smem;

    const int tid = threadIdx.x;
    const int w = tid >> 6, l = tid & 63;
    const int lr = l & 15, lg = l >> 4;
    const int px0 = blockIdx.x * 16, oy0 = blockIdx.y * 16;
    const int b = b0 + blockIdx.z;
    x1 += (size_t)blockIdx.z * X1_STRIDE;

    // stage lin via DMA (zero-stub for halo OOB)
    for (int q = tid; q < 18*18*8; q += 256) {
        int s = q & 7, t2 = q >> 3, c = t2 % 18, r = t2 / 18;
        int iy = oy0 - 1 + r, gx = px0 - 1 + c;
        const void* src = zbuf;
        if ((unsigned)iy < (unsigned)OHh && (unsigned)gx < (unsigned)OWw)
            src = &x1[((size_t)(iy*OWw + gx))*64 + (s ^ (c & 7))*8];
        async_load16(src, &lin[q]);
    }
    // stage lw[0] (tap 0) via DMA
    #pragma unroll
    for (int i = 0; i < 4; ++i) {
        const int q = tid + i*256, oc = q >> 3, s = q & 7;
        async_load16(&wt[((size_t)oc)*64 + (s ^ (oc & 7))*8], &lw[0][q]);
    }
    __syncthreads();

    f32x4 acc[4][8];
    #pragma unroll
    for (int t = 0; t < 4; ++t)
        #pragma unroll
        for (int n = 0; n < 8; ++n) acc[t][n] = (f32x4){0.f,0.f,0.f,0.f};

    #pragma unroll 1
    for (int tap = 0; tap < 9; ++tap) {
        const int ky = tap / 3, kx = tap - 3*ky;
        const int cur = tap & 1;
        if (tap < 8) {                          // DMA next tap's weights into the other buffer
            #pragma unroll
            for (int i = 0; i < 4; ++i) {
                const int q = tid + i*256, oc = q >> 3, s = q & 7;
                async_load16(&wt[((size_t)((tap+1)*128 + oc))*64 + (s ^ (oc & 7))*8],
                             &lw[cur ^ 1][q]);
            }
        }
        const int c = lr + kx;
        const int key = c & 7;
        bf16x8 af[4][2];
        #pragma unroll
        for (int t = 0; t < 4; ++t) {
            const int base = ((4*w + t + ky)*18 + c)*8;
            af[t][0] = as_bf16x8(lin[base + (lg ^ key)]);
            af[t][1] = as_bf16x8(lin[base + ((4 + lg) ^ key)]);
        }
        __builtin_amdgcn_s_setprio(1);
        #pragma unroll
        for (int n = 0; n < 8; ++n) {
            const int oc = n*16 + lr;
            const bf16x8 b0 = as_bf16x8(lw[cur][oc*8 + (lg ^ (oc & 7))]);
            const bf16x8 b1 = as_bf16x8(lw[cur][oc*8 + ((4 + lg) ^ (oc & 7))]);
            #pragma unroll
            for (int t = 0; t < 4; ++t) {
                acc[t][n] = __builtin_amdgcn_mfma_f32_16x16x32_bf16(af[t][0], b0, acc[t][n], 0, 0, 0);
                acc[t][n] = __builtin_amdgcn_mfma_f32_16x16x32_bf16(af[t][1], b1, acc[t][n], 0, 0, 0);
            }
        }
        __builtin_amdgcn_s_setprio(0);
        __syncthreads();                        // drains DMA; next tap's lw ready
    }

    float s[8], tt[8];
    #pragma unroll
    for (int n = 0; n < 8; ++n) {
        const int oc = n*16 + lr;
        s[n]  = ldin(g, oc, flags[14]) / sqrtf(ldin(v, oc, flags[17]) + 1e-5f);
        tt[n] = ldin(bb, oc, flags[15]) - ldin(m, oc, flags[16]) * s[n];
    }

    // ---- fused heads (r2-exact epilogue: pre-held hi/lo weights) ----
    float bias0, bias1;
    {
        int o = lr;
        bias0 = (o < 6) ? ldin(cls_b, o, flags[19]) : ldin(reg_b, o - 6, flags[21]);
        o = 16 + lr;
        bias1 = (o < 20) ? ldin(reg_b, o - 6, flags[21])
              : (o < 24) ? ldin(dir_b, o - 20, flags[23]) : 0.f;
    }
    uint4 wh[2][4], wl[2][4];
    #pragma unroll
    for (int n = 0; n < 2; ++n)
        #pragma unroll
        for (int ks = 0; ks < 4; ++ks) {
            const int ei = (n*16 + lr)*128 + ks*32 + lg*8;
            wh[n][ks] = *(const uint4*)&whh[ei];
            wl[n][ks] = *(const uint4*)&whl[ei];
        }

    __syncthreads();            // all waves done reading lin/lw before P overlay
    #pragma unroll
    for (int t = 0; t < 4; ++t) {
        const int pb = ((4*w + t)*16 + lg*4) * 128;
        #pragma unroll
        for (int n = 0; n < 8; ++n) {
            const int kk = 2*n + (lr >> 3), wi = lr & 7;
            #pragma unroll
            for (int r = 0; r < 4; ++r) {
                float val = fmaxf(fmaf(acc[t][n][r], s[n], tt[n]), 0.f);
                unsigned short h = f2b(val);
                P[pb + r*128 + ((kk ^ (lg*4 + r)) << 3) + wi] = h;
                acc[t][n][r] = val - b2f(h);
            }
        }
    }
    __syncthreads();

    f32x4 hacc[4][2];
    #pragma unroll
    for (int t = 0; t < 4; ++t) {
        hacc[t][0] = (f32x4){bias0, bias0, bias0, bias0};
        hacc[t][1] = (f32x4){bias1, bias1, bias1, bias1};
    }
    // pass 1: hi*Whi + hi*Wlo
    #pragma unroll
    for (int t = 0; t < 4; ++t) {
        const int mt = 4*w + t;
        bf16x8 pa[4];
        #pragma unroll
        for (int ks = 0; ks < 4; ++ks)
            pa[ks] = as_bf16x8(((const uint4*)P)[(mt*16 + lr)*16 + ((ks*4 + lg) ^ lr)]);
        #pragma unroll
        for (int n = 0; n < 2; ++n)
            #pragma unroll
            for (int ks = 0; ks < 4; ++ks) {
                hacc[t][n] = __builtin_amdgcn_mfma_f32_16x16x32_bf16(pa[ks], as_bf16x8(wh[n][ks]), hacc[t][n], 0, 0, 0);
                hacc[t][n] = __builtin_amdgcn_mfma_f32_16x16x32_bf16(pa[ks], as_bf16x8(wl[n][ks]), hacc[t][n], 0, 0, 0);
            }
    }
    __syncthreads();
    // fill P with lo
    #pragma unroll
    for (int t = 0; t < 4; ++t) {
        const int pb = ((4*w + t)*16 + lg*4) * 128;
        #pragma unroll
        for (int n = 0; n < 8; ++n) {
            const int kk = 2*n + (lr >> 3), wi = lr & 7;
            #pragma unroll
            for (int r = 0; r < 4; ++r)
                P[pb + r*128 + ((kk ^ (lg*4 + r)) << 3) + wi] = f2b(acc[t][n][r]);
        }
    }
    __syncthreads();
    // pass 2: lo*Whi
    #pragma unroll
    for (int t = 0; t < 4; ++t) {
        const int mt = 4*w + t;
        bf16x8 pa[4];
        #pragma unroll
        for (int ks = 0; ks < 4; ++ks)
            pa[ks] = as_bf16x8(((const uint4*)P)[(mt*16 + lr)*16 + ((ks*4 + lg) ^ lr)]);
        #pragma unroll
        for (int n = 0; n < 2; ++n)
            #pragma unroll
            for (int ks = 0; ks < 4; ++ks)
                hacc[t][n] = __builtin_amdgcn_mfma_f32_16x16x32_bf16(pa[ks], as_bf16x8(wh[n][ks]), hacc[t][n], 0, 0, 0);
    }

    const size_t regbase = (size_t)BATCH*6*HWp;
    const size_t dirbase = regbase + (size_t)BATCH*14*HWp;
    const int pxw = px0 + lg*4;
    #pragma unroll
    for (int n = 0; n < 2; ++n) {
        const int o = n*16 + lr;
        float* plane;
        bool valid = (pxw < OWw);
        if (o < 6)       plane = out + ((size_t)b*6 + o)*HWp;
        else if (o < 20) plane = out + regbase + ((size_t)b*14 + (o - 6))*HWp;
        else if (o < 24) plane = out + dirbase + ((size_t)b*4 + (o - 20))*HWp;
        else valid = false;
        if (!valid) continue;
        #pragma unroll
        for (int t = 0; t < 4; ++t) {
            const int oy = oy0 + 4*w + t;
            if (oy < OHh)
                *(float4*)&plane[(size_t)oy*OWw + pxw] = *(float4*)&hacc[t][n];
        }
    }
}

extern "C" void kernel_launch(void* const* d_in, const int* in_sizes, int n_in,
                              void* d_out, int out_size, void* d_ws, size_t ws_size,
                              hipStream_t stream) {
    static const int EXPECT[24] = {13824000,96000,48000,576,64,64,64,64,36864,
                                   64,64,64,64,73728,128,128,128,128,768,6,1792,14,512,4};
    const void* din[24];
    {
        bool used[24] = {false};
        int perm[24];
        bool ok = (n_in >= 24);
        if (ok) {
            for (int j = 0; j < 24 && ok; ++j) {
                perm[j] = -1;
                for (int i = 0; i < 24; ++i)
                    if (!used[i] && in_sizes[i] == EXPECT[j]) { perm[j] = i; used[i] = true; break; }
                if (perm[j] < 0) ok = false;
            }
        }
        for (int j = 0; j < 24; ++j) din[j] = d_in[ok ? perm[j] : j];
        if (!ok) {
            sentinel_kernel<<<1, 64, 0, stream>>>((float*)d_out, 13000.0f + n_in);
            return;
        }
    }
    const int* coords = (const int*)din[1];
    float* out = (float*)d_out;

    // layout: flags 256 | wt1 73,728 | wt2 147,456 | whh 8,192 | whl 8,192 | zbuf 64 |
    //         mask (nb x 32,768) | x1 bf16 (nb x 6,856,704) | canvas bf16 (nb x 27,426,816)
    const size_t X1B   = (size_t)HWp*64*2;          // 6,856,704
    const size_t CANB  = (size_t)NYg*NXg*64*2;      // 27,426,816
    const size_t MASKB = (size_t)MASKW*4;           // 32,768
    const size_t ZOFF  = 256 + 73728 + 147456 + 8192 + 8192;   // 237,824
    const size_t BASE  = ZOFF + 64;                 // 237,888
    const size_t NEED1 = BASE + MASKB + X1B + CANB;
    const size_t NEED4 = BASE + 4*(MASKB + X1B + CANB);
    if (ws_size < NEED1) {
        sentinel_kernel<<<1, 64, 0, stream>>>(out, 10000.0f + (float)(ws_size >> 20));
        return;
    }
    const int nb = (ws_size >= NEED4) ? 4 : 1;
    char* ws = (char*)d_ws;
    int* flags = (int*)ws;
    unsigned short* wt1 = (unsigned short*)(ws + 256);
    unsigned short* wt2 = (unsigned short*)(ws + 256 + 73728);
    unsigned short* whh = (unsigned short*)(ws + 256 + 73728 + 147456);
    unsigned short* whl = (unsigned short*)(ws + 256 + 73728 + 147456 + 8192);
    unsigned int*   zbuf = (unsigned int*)(ws + ZOFF);
    unsigned int*   maskbuf = (unsigned int*)(ws + BASE);
    unsigned short* x1  = (unsigned short*)(ws + BASE + (size_t)nb*MASKB);
    unsigned short* canvas = (unsigned short*)(ws + BASE + (size_t)nb*(MASKB + X1B));

    prep_weights<<<288, 256, 0, stream>>>(
        din[0], din[3], din[4], din[5], din[6], din[7],
        din[8], din[9], din[10], din[11], din[12],
        din[13], din[14], din[15], din[16], din[17],
        din[18], din[19], din[20], din[21], din[22], din[23],
        wt1, wt2, whh, whl, maskbuf, nb*MASKW, zbuf, flags);

    if (nb == 4) {
        pfn_scatter<<<dim3(NPIL/4, 4), 256, 0, stream>>>(
            din[0], coords, din[3], din[4], din[5], din[6], din[7], flags, 0, maskbuf, canvas);
        conv1_mfma<<<dim3(14, 16, 4), 256, 0, stream>>>(
            canvas, maskbuf, wt1, (const uint4*)zbuf,
            din[9], din[10], din[11], din[12], flags, x1);
        conv2_mfma<<<dim3(14, 16, 4), 256, 0, stream>>>(
            x1, wt2, whh, whl, (const uint4*)zbuf, din[14], din[15], din[16], din[17],
            din[19], din[21], din[23], flags, 0, out);
    } else {
        for (int b = 0; b < BATCH; ++b) {
            if (b) hipMemsetAsync(maskbuf, 0, MASKB, stream);   // b=0 zeroed by prep_weights
            pfn_scatter<<<dim3(NPIL/4, 1), 256, 0, stream>>>(
                din[0], coords, din[3], din[4], din[5], din[6], din[7], flags, b, maskbuf, canvas);
            conv1_mfma<<<dim3(14, 16, 1), 256, 0, stream>>>(
                canvas, maskbuf, wt1, (const uint4*)zbuf,
                din[9], din[10], din[11], din[12], flags, x1);
            conv2_mfma<<<dim3(14, 16, 1), 256, 0, stream>>>(
                x1, wt2, whh, whl, (const uint4*)zbuf, din[14], din[15], din[16], din[17],
                din[19], din[21], din[23], flags, b, out);
        }
    }
}

// Round 11
// 329.808 us; speedup vs baseline: 1.0744x; 1.0138x over previous
//
#include <hip/hip_runtime.h>

// ---------------- constants ----------------
#define BATCH 4
#define NPIL 12000
#define NPTS 32
#define NCH 9
#define NXg 432
#define NYg 496
#define OHh 248
#define OWw 216
#define HWp (OHh*OWw)          // 53568
#define CAN_STRIDE ((size_t)NYg*NXg*64)      // ushort elems (bf16 canvas)
#define X1_STRIDE  ((size_t)OHh*OWw*64)      // ushort elems (bf16 x1)
#define MASKW 8192                            // mask words per batch (padded)

typedef __bf16 bf16x8 __attribute__((ext_vector_type(8)));
typedef float  f32x4  __attribute__((ext_vector_type(4)));

__device__ __forceinline__ bf16x8 as_bf16x8(uint4 u) {
    union { uint4 u; bf16x8 b; } c; c.u = u; return c.b;
}

__device__ __forceinline__ float b2f(unsigned int u) {
    union { unsigned int i; float f; } x; x.i = (u & 0xffffu) << 16; return x.f;
}
__device__ __forceinline__ unsigned short f2b(float f) {
    union { float f; unsigned int i; } x; x.f = f;
    unsigned int r = x.i + 0x7fffu + ((x.i >> 16) & 1u);   // RNE
    return (unsigned short)(r >> 16);
}
__device__ __forceinline__ float ldin(const void* p, int i, int isbf) {
    return isbf ? b2f(((const unsigned short*)p)[i]) : ((const float*)p)[i];
}

// async global->LDS DMA, 16B per lane. LDS dest must be (wave-uniform base + lane*16);
// global source may be fully per-lane (m173 pattern: swizzle lives on the SOURCE address).
__device__ __forceinline__ void async_load16(const void* gsrc, void* ldst) {
    __builtin_amdgcn_global_load_lds(
        (const __attribute__((address_space(1))) unsigned char*)gsrc,
        (__attribute__((address_space(3))) unsigned char*)ldst, 16, 0, 0);
}

__global__ void sentinel_kernel(float* out, float val) {
    if (threadIdx.x == 0) out[0] = val;
}

// ---------------- dtype plausibility (robustness; all fp32 in practice) ----------------
__device__ __forceinline__ int plaus16(unsigned short h) {
    if ((h & 0x7fffu) == 0) return 1;
    unsigned e = (h >> 7) & 0xffu;
    return (e >= 106 && e <= 132) ? 1 : 0;
}

// ---------------- weight prep + integrated per-block dtype detection ----------------
__global__ __launch_bounds__(256) void prep_weights(
    const void* q0,  const void* q1,  const void* q2,  const void* q3,
    const void* q4,  const void* q5,  const void* q6,  const void* q7,
    const void* q8,  const void* q9,  const void* q10, const void* q11,
    const void* q12, const void* q13, const void* q14, const void* q15,
    const void* q16, const void* q17, const void* q18, const void* q19,
    const void* q20, const void* q21,
    unsigned short* __restrict__ wt1, unsigned short* __restrict__ wt2,
    unsigned short* __restrict__ whh, unsigned short* __restrict__ whl,
    unsigned int* __restrict__ mask, int mask_words,
    unsigned int* __restrict__ zbuf,
    int* __restrict__ flags_out)
{
    __shared__ int votes[22];
    __shared__ int sflags[24];
    const void* ptrs[22] = {q0,q1,q2,q3,q4,q5,q6,q7,q8,q9,q10,q11,
                            q12,q13,q14,q15,q16,q17,q18,q19,q20,q21};
    const int Ks[22]   = {64,64,32,32,32,32,64,32,32,32,32,64,64,64,64,64,64,3,64,7,64,2};
    const int didx[22] = {0,3,4,5,6,7,8,9,10,11,12,13,14,15,16,17,18,19,20,21,22,23};
    const int tid = threadIdx.x;
    if (tid < 22) votes[tid] = 0;
    if (tid < 24) sflags[tid] = 0;
    __syncthreads();
    #pragma unroll 1
    for (int wb = 0; wb < 4; ++wb) {          // 4 windows cover cumulative offset space (972)
        const int vt = wb*256 + tid;
        int off = 0;
        #pragma unroll                         // full unroll -> constant ptrs[] indices (SGPR)
        for (int t = 0; t < 22; ++t) {
            if (vt >= off && vt < off + Ks[t]) {
                unsigned w = ((const unsigned*)ptrs[t])[vt - off];
                if (plaus16((unsigned short)w) && plaus16((unsigned short)(w >> 16)))
                    atomicAdd(&votes[t], 1);
            }
            off += Ks[t];
        }
    }
    __syncthreads();
    if (tid < 22) {
        int isbf;
        if (tid == 17 || tid == 19 || tid == 21) {
            int pv = votes[17] + votes[19] + votes[21];
            isbf = (pv * 4 >= 3 * 12);
        } else {
            isbf = (votes[tid] * 4 >= 3 * Ks[tid]);
        }
        sflags[didx[tid]] = isbf;
    }
    __syncthreads();
    if (blockIdx.x == 0 && tid < 24) flags_out[tid] = sflags[tid];

    const int f1 = sflags[8], f2 = sflags[13];
    int i = blockIdx.x * 256 + tid;
    if (i < mask_words) mask[i] = 0u;
    if (i < 16) zbuf[i] = 0u;
    if (i < 64*64*9) {
        int kx = i % 3; int t = i / 3; int ky = t % 3; t /= 3; int ic = t % 64; int oc = t / 64;
        wt1[((size_t)(ky*3 + kx)*64 + oc)*64 + ic] = f2b(ldin(q6, i, f1));      // q6 = w1
    }
    if (i < 128*64*9) {
        int kx = i % 3; int t = i / 3; int ky = t % 3; t /= 3; int ic = t % 64; int oc = t / 64;
        wt2[((size_t)(ky*3 + kx)*128 + oc)*64 + ic] = f2b(ldin(q11, i, f2));    // q11 = w2
    }
    if (i < 32*128) {
        int ic = i & 127, o = i >> 7;
        float wv = 0.f;
        if (o < 6)       wv = ldin(q16, o*128 + ic, sflags[18]);                // cls_w
        else if (o < 20) wv = ldin(q18, (o-6)*128 + ic, sflags[20]);            // reg_w
        else if (o < 24) wv = ldin(q20, (o-20)*128 + ic, sflags[22]);           // dir_w
        unsigned short hi = f2b(wv);
        whh[i] = hi;
        whl[i] = f2b(wv - b2f(hi));
    }
}

// ---------------- PFN + scatter, canvas NHWC bf16 [NY,NX,64] + occupancy mask ----------------
__global__ __launch_bounds__(256) void pfn_scatter(
    const void* __restrict__ pillars, const int* __restrict__ coords,
    const void* __restrict__ pfn_w,
    const void* __restrict__ g, const void* __restrict__ bb,
    const void* __restrict__ m, const void* __restrict__ v,
    const int* __restrict__ flags, int b0,
    unsigned int* __restrict__ mask,
    unsigned short* __restrict__ canvas)
{
    __shared__ float lds[4][NPTS*NCH];
    const int wslot = threadIdx.x >> 6;
    const int lane  = threadIdx.x & 63;
    const int p = blockIdx.x * 4 + wslot;
    const int b = b0 + blockIdx.y;
    canvas += (size_t)blockIdx.y * CAN_STRIDE;
    mask   += (size_t)blockIdx.y * MASKW;
    const size_t pg = (size_t)b * NPIL + p;

    if (flags[0]) {
        const unsigned short* src = (const unsigned short*)pillars + pg * (NPTS*NCH);
        for (int idx = lane; idx < NPTS*NCH; idx += 64) lds[wslot][idx] = b2f(src[idx]);
    } else {
        const float4* src = (const float4*)((const float*)pillars + pg * (NPTS*NCH));
        for (int idx = lane; idx < (NPTS*NCH)/4; idx += 64)
            *(float4*)&lds[wslot][idx*4] = src[idx];
    }
    float w[NCH];
    const int fW = flags[3];
    #pragma unroll
    for (int c = 0; c < NCH; ++c) w[c] = ldin(pfn_w, lane*NCH + c, fW);
    float s = ldin(g, lane, flags[4]) / sqrtf(ldin(v, lane, flags[7]) + 1e-5f);
    float t = ldin(bb, lane, flags[5]) - ldin(m, lane, flags[6]) * s;
    __syncthreads();

    float mx = 0.0f;
    #pragma unroll 4
    for (int n = 0; n < NPTS; ++n) {
        const float* r = &lds[wslot][n*NCH];
        float acc = r[0] * w[0];
        #pragma unroll
        for (int c = 1; c < NCH; ++c) acc = fmaf(r[c], w[c], acc);
        mx = fmaxf(mx, fmaxf(fmaf(acc, s, t), 0.0f));
    }
    const int cx = coords[pg*2], cy = coords[pg*2 + 1];
    if (cx + cy != 0 && cx >= 0 && cx < NXg && cy >= 0 && cy < NYg) {
        const int cell = cy*NXg + cx;
        canvas[(size_t)cell*64 + lane] = f2b(mx);
        if (lane == 0) atomicOr(&mask[cell >> 5], 1u << (cell & 31));
    }
}

// B-fragment loader for conv1 (direct from L2-resident wt1)
#define LDB1(buf, tap, ks) { \
    _Pragma("unroll") \
    for (int j_ = 0; j_ < 4; ++j_) \
        buf[j_] = *(const uint4*)&wt[((size_t)((tap)*64 + j_*16 + lr))*64 + (ks)*32 + lg*8]; \
}

// ---------------- conv1 (MFMA): canvas bf16 -> x1 bf16 [248,216,64], stride 2 ----------------
// Odd/even row-sharing: ky=0 reads odd canvas rows 2oy-1, ky=2 reads odd rows 2oy+1 (16 of
// 17 shared!), ky=1 reads even rows. Stage 17 odd rows ONCE -> compute 6 taps (ky=0,2);
// restage 16 even rows -> compute ky=1. Staging chunks 12,672 -> 8,712 (-31%), barriers
// 6 -> 4 vs per-ky staging. LDS 71,808 B -> 2 blk/CU. DMA staging (linear dest,
// inverse-swizzled source, zero-stub), mask-gated. B from wt1 w/ 2-phase reg prefetch.
__global__ __launch_bounds__(256, 2) void conv1_mfma(
    const unsigned short* __restrict__ canvas,
    const unsigned int* __restrict__ mask,
    const unsigned short* __restrict__ wt,     // bf16 [9][64 oc][64 ic]
    const uint4* __restrict__ zbuf,
    const void* __restrict__ g, const void* __restrict__ bb,
    const void* __restrict__ m, const void* __restrict__ v,
    const int* __restrict__ flags,
    unsigned short* __restrict__ x1)
{
    __shared__ __align__(16) uint4 lin[17*33*8];   // 71,808 B
    const int tid = threadIdx.x;
    const int w = tid >> 6, l = tid & 63;
    const int lr = l & 15, lg = l >> 4;
    const int px0 = blockIdx.x * 16, oy0 = blockIdx.y * 16;
    canvas += (size_t)blockIdx.z * CAN_STRIDE;
    mask   += (size_t)blockIdx.z * MASKW;
    x1     += (size_t)blockIdx.z * X1_STRIDE;

    f32x4 acc[4][4];
    #pragma unroll
    for (int t = 0; t < 4; ++t)
        #pragma unroll
        for (int n = 0; n < 4; ++n) acc[t][n] = (f32x4){0.f,0.f,0.f,0.f};

    uint4 wbA[4], wbB[4];
    // phase-A tap order: (0,0),(2,0),(0,1),(2,1),(0,2),(2,2) -> taps {0,6,1,7,2,8}
    LDB1(wbA, 0, 0);

    // ---- phase A: stage 17 odd rows (iy = 2*oy0 - 1 + 2j) ----
    for (int q = tid; q < 17*33*8; q += 256) {
        int s = q & 7, t2 = q >> 3, c = t2 % 33, j = t2 / 33;
        int iy = 2*oy0 - 1 + 2*j, gx = 2*px0 - 1 + c;
        const void* src = zbuf;
        if ((unsigned)iy < (unsigned)NYg && (unsigned)gx < (unsigned)NXg) {
            const int cell = iy*NXg + gx;
            if ((mask[cell >> 5] >> (cell & 31)) & 1u)
                src = &canvas[(size_t)cell*64 + (s ^ ((c >> 1) & 7))*8];
        }
        async_load16(src, &lin[q]);
    }
    __syncthreads();                           // drains DMA
    {
        const int SEQA[6] = {0, 6, 1, 7, 2, 8};
        #pragma unroll
        for (int i = 0; i < 6; ++i) {
            const int tap = SEQA[i];
            const int kx = tap % 3;
            const int joff = (tap >= 6) ? 1 : 0;   // ky=2 reads odd row j=m+1
            const int c = 2*lr + kx;
            const int key = (c >> 1) & 7;
            LDB1(wbB, tap, 1);
            __builtin_amdgcn_s_setprio(1);
            #pragma unroll
            for (int t = 0; t < 4; ++t) {
                const int base = ((4*w + t + joff)*33 + c)*8;
                bf16x8 a0 = as_bf16x8(lin[base + (lg ^ key)]);
                #pragma unroll
                for (int n = 0; n < 4; ++n)
                    acc[t][n] = __builtin_amdgcn_mfma_f32_16x16x32_bf16(a0, as_bf16x8(wbA[n]), acc[t][n], 0, 0, 0);
            }
            __builtin_amdgcn_s_setprio(0);
            LDB1(wbA, (i < 5) ? SEQA[i + 1] : 3, 0);   // i=5 prefetches phase-B tap 3
            __builtin_amdgcn_s_setprio(1);
            #pragma unroll
            for (int t = 0; t < 4; ++t) {
                const int base = ((4*w + t + joff)*33 + c)*8;
                bf16x8 a1 = as_bf16x8(lin[base + ((4 + lg) ^ key)]);
                #pragma unroll
                for (int n = 0; n < 4; ++n)
                    acc[t][n] = __builtin_amdgcn_mfma_f32_16x16x32_bf16(a1, as_bf16x8(wbB[n]), acc[t][n], 0, 0, 0);
            }
            __builtin_amdgcn_s_setprio(0);
        }
    }

    // ---- phase B: stage 16 even rows (iy = 2*oy0 + 2j), compute ky=1 ----
    __syncthreads();                           // drain phase-A readers
    for (int q = tid; q < 16*33*8; q += 256) {
        int s = q & 7, t2 = q >> 3, c = t2 % 33, j = t2 / 33;
        int iy = 2*oy0 + 2*j, gx = 2*px0 - 1 + c;
        const void* src = zbuf;
        if ((unsigned)iy < (unsigned)NYg && (unsigned)gx < (unsigned)NXg) {
            const int cell = iy*NXg + gx;
            if ((mask[cell >> 5] >> (cell & 31)) & 1u)
                src = &canvas[(size_t)cell*64 + (s ^ ((c >> 1) & 7))*8];
        }
        async_load16(src, &lin[q]);
    }
    __syncthreads();
    #pragma unroll
    for (int tap = 3; tap < 6; ++tap) {        // ky=1, kx = tap-3
        const int kx = tap - 3;
        const int c = 2*lr + kx;
        const int key = (c >> 1) & 7;
        LDB1(wbB, tap, 1);
        __builtin_amdgcn_s_setprio(1);
        #pragma unroll
        for (int t = 0; t < 4; ++t) {
            const int base = ((4*w + t)*33 + c)*8;
            bf16x8 a0 = as_bf16x8(lin[base + (lg ^ key)]);
            #pragma unroll
            for (int n = 0; n < 4; ++n)
                acc[t][n] = __builtin_amdgcn_mfma_f32_16x16x32_bf16(a0, as_bf16x8(wbA[n]), acc[t][n], 0, 0, 0);
        }
        __builtin_amdgcn_s_setprio(0);
        if (tap < 5) LDB1(wbA, tap + 1, 0);
        __builtin_amdgcn_s_setprio(1);
        #pragma unroll
        for (int t = 0; t < 4; ++t) {
            const int base = ((4*w + t)*33 + c)*8;
            bf16x8 a1 = as_bf16x8(lin[base + ((4 + lg) ^ key)]);
            #pragma unroll
            for (int n = 0; n < 4; ++n)
                acc[t][n] = __builtin_amdgcn_mfma_f32_16x16x32_bf16(a1, as_bf16x8(wbB[n]), acc[t][n], 0, 0, 0);
        }
        __builtin_amdgcn_s_setprio(0);
    }

    float s[4], tt[4];
    #pragma unroll
    for (int n = 0; n < 4; ++n) {
        const int oc = n*16 + lr;
        s[n]  = ldin(g, oc, flags[9]) / sqrtf(ldin(v, oc, flags[12]) + 1e-5f);
        tt[n] = ldin(bb, oc, flags[10]) - ldin(m, oc, flags[11]) * s[n];
    }
    // D: col = lr = oc, row = lg*4+r = px
    #pragma unroll
    for (int t = 0; t < 4; ++t) {
        const int oy = oy0 + 4*w + t;
        if (oy >= OHh) continue;
        #pragma unroll
        for (int r = 0; r < 4; ++r) {
            const int px = px0 + lg*4 + r;
            if (px >= OWw) continue;
            unsigned short* orow = &x1[((size_t)oy*OWw + px)*64 + lr];
            #pragma unroll
            for (int n = 0; n < 4; ++n)
                orow[n*16] = f2b(fmaxf(fmaf(acc[t][n][r], s[n], tt[n]), 0.f));
        }
    }
}

// ---------------- conv2 (MFMA) + fused heads — r8/r10-exact ----------------
__global__ __launch_bounds__(256, 2) void conv2_mfma(
    const unsigned short* __restrict__ x1,
    const unsigned short* __restrict__ wt,     // bf16 [9][128 oc][64 ic]
    const unsigned short* __restrict__ whh,    // bf16 [32 o][128 ic] head W hi
    const unsigned short* __restrict__ whl,    // bf16 [32 o][128 ic] head W lo
    const uint4* __restrict__ zbuf,
    const void* __restrict__ g, const void* __restrict__ bb,
    const void* __restrict__ m, const void* __restrict__ v,
    const void* __restrict__ cls_b, const void* __restrict__ reg_b, const void* __restrict__ dir_b,
    const int* __restrict__ flags, int b0,
    float* __restrict__ out)
{
    __shared__ __align__(16) char smem[74240];     // lin 41,472 | lw 32,768 ; P overlays 65,536
    uint4* lin = (uint4*)smem;
    uint4 (*lw)[128*8] = (uint4 (*)[128*8])(smem + 41472);
    unsigned short* P = (unsigned short*)smem;

    const int tid = threadIdx.x;
    const int w = tid >> 6, l = tid & 63;
    const int lr = l & 15, lg = l >> 4;
    const int px0 = blockIdx.x * 16, oy0 = blockIdx.y * 16;
    const int b = b0 + blockIdx.z;
    x1 += (size_t)blockIdx.z * X1_STRIDE;

    // stage lin via DMA (zero-stub for halo OOB)
    for (int q = tid; q < 18*18*8; q += 256) {
        int s = q & 7, t2 = q >> 3, c = t2 % 18, r = t2 / 18;
        int iy = oy0 - 1 + r, gx = px0 - 1 + c;
        const void* src = zbuf;
        if ((unsigned)iy < (unsigned)OHh && (unsigned)gx < (unsigned)OWw)
            src = &x1[((size_t)(iy*OWw + gx))*64 + (s ^ (c & 7))*8];
        async_load16(src, &lin[q]);
    }
    // stage lw[0] (tap 0) via DMA
    #pragma unroll
    for (int i = 0; i < 4; ++i) {
        const int q = tid + i*256, oc = q >> 3, s = q & 7;
        async_load16(&wt[((size_t)oc)*64 + (s ^ (oc & 7))*8], &lw[0][q]);
    }
    __syncthreads();

    f32x4 acc[4][8];
    #pragma unroll
    for (int t = 0; t < 4; ++t)
        #pragma unroll
        for (int n = 0; n < 8; ++n) acc[t][n] = (f32x4){0.f,0.f,0.f,0.f};

    #pragma unroll 1
    for (int tap = 0; tap < 9; ++tap) {
        const int ky = tap / 3, kx = tap - 3*ky;
        const int cur = tap & 1;
        if (tap < 8) {                          // DMA next tap's weights into the other buffer
            #pragma unroll
            for (int i = 0; i < 4; ++i) {
                const int q = tid + i*256, oc = q >> 3, s = q & 7;
                async_load16(&wt[((size_t)((tap+1)*128 + oc))*64 + (s ^ (oc & 7))*8],
                             &lw[cur ^ 1][q]);
            }
        }
        const int c = lr + kx;
        const int key = c & 7;
        bf16x8 af[4][2];
        #pragma unroll
        for (int t = 0; t < 4; ++t) {
            const int base = ((4*w + t + ky)*18 + c)*8;
            af[t][0] = as_bf16x8(lin[base + (lg ^ key)]);
            af[t][1] = as_bf16x8(lin[base + ((4 + lg) ^ key)]);
        }
        __builtin_amdgcn_s_setprio(1);
        #pragma unroll
        for (int n = 0; n < 8; ++n) {
            const int oc = n*16 + lr;
            const bf16x8 b0 = as_bf16x8(lw[cur][oc*8 + (lg ^ (oc & 7))]);
            const bf16x8 b1 = as_bf16x8(lw[cur][oc*8 + ((4 + lg) ^ (oc & 7))]);
            #pragma unroll
            for (int t = 0; t < 4; ++t) {
                acc[t][n] = __builtin_amdgcn_mfma_f32_16x16x32_bf16(af[t][0], b0, acc[t][n], 0, 0, 0);
                acc[t][n] = __builtin_amdgcn_mfma_f32_16x16x32_bf16(af[t][1], b1, acc[t][n], 0, 0, 0);
            }
        }
        __builtin_amdgcn_s_setprio(0);
        __syncthreads();                        // drains DMA; next tap's lw ready
    }

    float s[8], tt[8];
    #pragma unroll
    for (int n = 0; n < 8; ++n) {
        const int oc = n*16 + lr;
        s[n]  = ldin(g, oc, flags[14]) / sqrtf(ldin(v, oc, flags[17]) + 1e-5f);
        tt[n] = ldin(bb, oc, flags[15]) - ldin(m, oc, flags[16]) * s[n];
    }

    // ---- fused heads (r2-exact epilogue: pre-held hi/lo weights) ----
    float bias0, bias1;
    {
        int o = lr;
        bias0 = (o < 6) ? ldin(cls_b, o, flags[19]) : ldin(reg_b, o - 6, flags[21]);
        o = 16 + lr;
        bias1 = (o < 20) ? ldin(reg_b, o - 6, flags[21])
              : (o < 24) ? ldin(dir_b, o - 20, flags[23]) : 0.f;
    }
    uint4 wh[2][4], wl[2][4];
    #pragma unroll
    for (int n = 0; n < 2; ++n)
        #pragma unroll
        for (int ks = 0; ks < 4; ++ks) {
            const int ei = (n*16 + lr)*128 + ks*32 + lg*8;
            wh[n][ks] = *(const uint4*)&whh[ei];
            wl[n][ks] = *(const uint4*)&whl[ei];
        }

    __syncthreads();            // all waves done reading lin/lw before P overlay
    #pragma unroll
    for (int t = 0; t < 4; ++t) {
        const int pb = ((4*w + t)*16 + lg*4) * 128;
        #pragma unroll
        for (int n = 0; n < 8; ++n) {
            const int kk = 2*n + (lr >> 3), wi = lr & 7;
            #pragma unroll
            for (int r = 0; r < 4; ++r) {
                float val = fmaxf(fmaf(acc[t][n][r], s[n], tt[n]), 0.f);
                unsigned short h = f2b(val);
                P[pb + r*128 + ((kk ^ (lg*4 + r)) << 3) + wi] = h;
                acc[t][n][r] = val - b2f(h);
            }
        }
    }
    __syncthreads();

    f32x4 hacc[4][2];
    #pragma unroll
    for (int t = 0; t < 4; ++t) {
        hacc[t][0] = (f32x4){bias0, bias0, bias0, bias0};
        hacc[t][1] = (f32x4){bias1, bias1, bias1, bias1};
    }
    // pass 1: hi*Whi + hi*Wlo
    #pragma unroll
    for (int t = 0; t < 4; ++t) {
        const int mt = 4*w + t;
        bf16x8 pa[4];
        #pragma unroll
        for (int ks = 0; ks < 4; ++ks)
            pa[ks] = as_bf16x8(((const uint4*)P)[(mt*16 + lr)*16 + ((ks*4 + lg) ^ lr)]);
        #pragma unroll
        for (int n = 0; n < 2; ++n)
            #pragma unroll
            for (int ks = 0; ks < 4; ++ks) {
                hacc[t][n] = __builtin_amdgcn_mfma_f32_16x16x32_bf16(pa[ks], as_bf16x8(wh[n][ks]), hacc[t][n], 0, 0, 0);
                hacc[t][n] = __builtin_amdgcn_mfma_f32_16x16x32_bf16(pa[ks], as_bf16x8(wl[n][ks]), hacc[t][n], 0, 0, 0);
            }
    }
    __syncthreads();
    // fill P with lo
    #pragma unroll
    for (int t = 0; t < 4; ++t) {
        const int pb = ((4*w + t)*16 + lg*4) * 128;
        #pragma unroll
        for (int n = 0; n < 8; ++n) {
            const int kk = 2*n + (lr >> 3), wi = lr & 7;
            #pragma unroll
            for (int r = 0; r < 4; ++r)
                P[pb + r*128 + ((kk ^ (lg*4 + r)) << 3) + wi] = f2b(acc[t][n][r]);
        }
    }
    __syncthreads();
    // pass 2: lo*Whi
    #pragma unroll
    for (int t = 0; t < 4; ++t) {
        const int mt = 4*w + t;
        bf16x8 pa[4];
        #pragma unroll
        for (int ks = 0; ks < 4; ++ks)
            pa[ks] = as_bf16x8(((const uint4*)P)[(mt*16 + lr)*16 + ((ks*4 + lg) ^ lr)]);
        #pragma unroll
        for (int n = 0; n < 2; ++n)
            #pragma unroll
            for (int ks = 0; ks < 4; ++ks)
                hacc[t][n] = __builtin_amdgcn_mfma_f32_16x16x32_bf16(pa[ks], as_bf16x8(wh[n][ks]), hacc[t][n], 0, 0, 0);
    }

    const size_t regbase = (size_t)BATCH*6*HWp;
    const size_t dirbase = regbase + (size_t)BATCH*14*HWp;
    const int pxw = px0 + lg*4;
    #pragma unroll
    for (int n = 0; n < 2; ++n) {
        const int o = n*16 + lr;
        float* plane;
        bool valid = (pxw < OWw);
        if (o < 6)       plane = out + ((size_t)b*6 + o)*HWp;
        else if (o < 20) plane = out + regbase + ((size_t)b*14 + (o - 6))*HWp;
        else if (o < 24) plane = out + dirbase + ((size_t)b*4 + (o - 20))*HWp;
        else valid = false;
        if (!valid) continue;
        #pragma unroll
        for (int t = 0; t < 4; ++t) {
            const int oy = oy0 + 4*w + t;
            if (oy < OHh)
                *(float4*)&plane[(size_t)oy*OWw + pxw] = *(float4*)&hacc[t][n];
        }
    }
}

extern "C" void kernel_launch(void* const* d_in, const int* in_sizes, int n_in,
                              void* d_out, int out_size, void* d_ws, size_t ws_size,
                              hipStream_t stream) {
    static const int EXPECT[24] = {13824000,96000,48000,576,64,64,64,64,36864,
                                   64,64,64,64,73728,128,128,128,128,768,6,1792,14,512,4};
    const void* din[24];
    {
        bool used[24] = {false};
        int perm[24];
        bool ok = (n_in >= 24);
        if (ok) {
            for (int j = 0; j < 24 && ok; ++j) {
                perm[j] = -1;
                for (int i = 0; i < 24; ++i)
                    if (!used[i] && in_sizes[i] == EXPECT[j]) { perm[j] = i; used[i] = true; break; }
                if (perm[j] < 0) ok = false;
            }
        }
        for (int j = 0; j < 24; ++j) din[j] = d_in[ok ? perm[j] : j];
        if (!ok) {
            sentinel_kernel<<<1, 64, 0, stream>>>((float*)d_out, 13000.0f + n_in);
            return;
        }
    }
    const int* coords = (const int*)din[1];
    float* out = (float*)d_out;

    // layout: flags 256 | wt1 73,728 | wt2 147,456 | whh 8,192 | whl 8,192 | zbuf 64 |
    //         mask (nb x 32,768) | x1 bf16 (nb x 6,856,704) | canvas bf16 (nb x 27,426,816)
    const size_t X1B   = (size_t)HWp*64*2;          // 6,856,704
    const size_t CANB  = (size_t)NYg*NXg*64*2;      // 27,426,816
    const size_t MASKB = (size_t)MASKW*4;           // 32,768
    const size_t ZOFF  = 256 + 73728 + 147456 + 8192 + 8192;   // 237,824
    const size_t BASE  = ZOFF + 64;                 // 237,888
    const size_t NEED1 = BASE + MASKB + X1B + CANB;
    const size_t NEED4 = BASE + 4*(MASKB + X1B + CANB);
    if (ws_size < NEED1) {
        sentinel_kernel<<<1, 64, 0, stream>>>(out, 10000.0f + (float)(ws_size >> 20));
        return;
    }
    const int nb = (ws_size >= NEED4) ? 4 : 1;
    char* ws = (char*)d_ws;
    int* flags = (int*)ws;
    unsigned short* wt1 = (unsigned short*)(ws + 256);
    unsigned short* wt2 = (unsigned short*)(ws + 256 + 73728);
    unsigned short* whh = (unsigned short*)(ws + 256 + 73728 + 147456);
    unsigned short* whl = (unsigned short*)(ws + 256 + 73728 + 147456 + 8192);
    unsigned int*   zbuf = (unsigned int*)(ws + ZOFF);
    unsigned int*   maskbuf = (unsigned int*)(ws + BASE);
    unsigned short* x1  = (unsigned short*)(ws + BASE + (size_t)nb*MASKB);
    unsigned short* canvas = (unsigned short*)(ws + BASE + (size_t)nb*(MASKB + X1B));

    prep_weights<<<288, 256, 0, stream>>>(
        din[0], din[3], din[4], din[5], din[6], din[7],
        din[8], din[9], din[10], din[11], din[12],
        din[13], din[14], din[15], din[16], din[17],
        din[18], din[19], din[20], din[21], din[22], din[23],
        wt1, wt2, whh, whl, maskbuf, nb*MASKW, zbuf, flags);

    if (nb == 4) {
        pfn_scatter<<<dim3(NPIL/4, 4), 256, 0, stream>>>(
            din[0], coords, din[3], din[4], din[5], din[6], din[7], flags, 0, maskbuf, canvas);
        conv1_mfma<<<dim3(14, 16, 4), 256, 0, stream>>>(
            canvas, maskbuf, wt1, (const uint4*)zbuf,
            din[9], din[10], din[11], din[12], flags, x1);
        conv2_mfma<<<dim3(14, 16, 4), 256, 0, stream>>>(
            x1, wt2, whh, whl, (const uint4*)zbuf, din[14], din[15], din[16], din[17],
            din[19], din[21], din[23], flags, 0, out);
    } else {
        for (int b = 0; b < BATCH; ++b) {
            if (b) hipMemsetAsync(maskbuf, 0, MASKB, stream);   // b=0 zeroed by prep_weights
            pfn_scatter<<<dim3(NPIL/4, 1), 256, 0, stream>>>(
                din[0], coords, din[3], din[4], din[5], din[6], din[7], flags, b, maskbuf, canvas);
            conv1_mfma<<<dim3(14, 16, 1), 256, 0, stream>>>(
                canvas, maskbuf, wt1, (const uint4*)zbuf,
                din[9], din[10], din[11], din[12], flags, x1);
            conv2_mfma<<<dim3(14, 16, 1), 256, 0, stream>>>(
                x1, wt2, whh, whl, (const uint4*)zbuf, din[14], din[15], din[16], din[17],
                din[19], din[21], din[23], flags, b, out);
        }
    }
}

// Round 12
// 321.222 us; speedup vs baseline: 1.1031x; 1.0267x over previous
//
#include <hip/hip_runtime.h>

// ---------------- constants ----------------
#define BATCH 4
#define NPIL 12000
#define NPTS 32
#define NCH 9
#define NXg 432
#define NYg 496
#define OHh 248
#define OWw 216
#define HWp (OHh*OWw)          // 53568
#define CAN_STRIDE ((size_t)NYg*NXg*64)      // ushort elems (bf16 canvas)
#define X1_STRIDE  ((size_t)OHh*OWw*64)      // ushort elems (bf16 x1)
#define MASKW 8192                            // mask words per batch (padded)

typedef __bf16 bf16x8 __attribute__((ext_vector_type(8)));
typedef float  f32x4  __attribute__((ext_vector_type(4)));

__device__ __forceinline__ bf16x8 as_bf16x8(uint4 u) {
    union { uint4 u; bf16x8 b; } c; c.u = u; return c.b;
}

__device__ __forceinline__ float b2f(unsigned int u) {
    union { unsigned int i; float f; } x; x.i = (u & 0xffffu) << 16; return x.f;
}
__device__ __forceinline__ unsigned short f2b(float f) {
    union { float f; unsigned int i; } x; x.f = f;
    unsigned int r = x.i + 0x7fffu + ((x.i >> 16) & 1u);   // RNE
    return (unsigned short)(r >> 16);
}
__device__ __forceinline__ float ldin(const void* p, int i, int isbf) {
    return isbf ? b2f(((const unsigned short*)p)[i]) : ((const float*)p)[i];
}

// async global->LDS DMA, 16B per lane. LDS dest must be (wave-uniform base + lane*16);
// global source may be fully per-lane (m173 pattern: swizzle lives on the SOURCE address).
__device__ __forceinline__ void async_load16(const void* gsrc, void* ldst) {
    __builtin_amdgcn_global_load_lds(
        (const __attribute__((address_space(1))) unsigned char*)gsrc,
        (__attribute__((address_space(3))) unsigned char*)ldst, 16, 0, 0);
}

__global__ void sentinel_kernel(float* out, float val) {
    if (threadIdx.x == 0) out[0] = val;
}

// ---------------- dtype plausibility (robustness; all fp32 in practice) ----------------
__device__ __forceinline__ int plaus16(unsigned short h) {
    if ((h & 0x7fffu) == 0) return 1;
    unsigned e = (h >> 7) & 0xffu;
    return (e >= 106 && e <= 132) ? 1 : 0;
}

// ---------------- weight prep + integrated per-block dtype detection ----------------
__global__ __launch_bounds__(256) void prep_weights(
    const void* q0,  const void* q1,  const void* q2,  const void* q3,
    const void* q4,  const void* q5,  const void* q6,  const void* q7,
    const void* q8,  const void* q9,  const void* q10, const void* q11,
    const void* q12, const void* q13, const void* q14, const void* q15,
    const void* q16, const void* q17, const void* q18, const void* q19,
    const void* q20, const void* q21,
    unsigned short* __restrict__ wt1, unsigned short* __restrict__ wt2,
    unsigned short* __restrict__ whh, unsigned short* __restrict__ whl,
    unsigned int* __restrict__ mask, int mask_words,
    unsigned int* __restrict__ zbuf,
    int* __restrict__ flags_out)
{
    __shared__ int votes[22];
    __shared__ int sflags[24];
    const void* ptrs[22] = {q0,q1,q2,q3,q4,q5,q6,q7,q8,q9,q10,q11,
                            q12,q13,q14,q15,q16,q17,q18,q19,q20,q21};
    const int Ks[22]   = {64,64,32,32,32,32,64,32,32,32,32,64,64,64,64,64,64,3,64,7,64,2};
    const int didx[22] = {0,3,4,5,6,7,8,9,10,11,12,13,14,15,16,17,18,19,20,21,22,23};
    const int tid = threadIdx.x;
    if (tid < 22) votes[tid] = 0;
    if (tid < 24) sflags[tid] = 0;
    __syncthreads();
    #pragma unroll 1
    for (int wb = 0; wb < 4; ++wb) {          // 4 windows cover cumulative offset space (972)
        const int vt = wb*256 + tid;
        int off = 0;
        #pragma unroll                         // full unroll -> constant ptrs[] indices (SGPR)
        for (int t = 0; t < 22; ++t) {
            if (vt >= off && vt < off + Ks[t]) {
                unsigned w = ((const unsigned*)ptrs[t])[vt - off];
                if (plaus16((unsigned short)w) && plaus16((unsigned short)(w >> 16)))
                    atomicAdd(&votes[t], 1);
            }
            off += Ks[t];
        }
    }
    __syncthreads();
    if (tid < 22) {
        int isbf;
        if (tid == 17 || tid == 19 || tid == 21) {
            int pv = votes[17] + votes[19] + votes[21];
            isbf = (pv * 4 >= 3 * 12);
        } else {
            isbf = (votes[tid] * 4 >= 3 * Ks[tid]);
        }
        sflags[didx[tid]] = isbf;
    }
    __syncthreads();
    if (blockIdx.x == 0 && tid < 24) flags_out[tid] = sflags[tid];

    const int f1 = sflags[8], f2 = sflags[13];
    int i = blockIdx.x * 256 + tid;
    if (i < mask_words) mask[i] = 0u;
    if (i < 16) zbuf[i] = 0u;
    if (i < 64*64*9) {
        int kx = i % 3; int t = i / 3; int ky = t % 3; t /= 3; int ic = t % 64; int oc = t / 64;
        wt1[((size_t)(ky*3 + kx)*64 + oc)*64 + ic] = f2b(ldin(q6, i, f1));      // q6 = w1
    }
    if (i < 128*64*9) {
        int kx = i % 3; int t = i / 3; int ky = t % 3; t /= 3; int ic = t % 64; int oc = t / 64;
        wt2[((size_t)(ky*3 + kx)*128 + oc)*64 + ic] = f2b(ldin(q11, i, f2));    // q11 = w2
    }
    if (i < 32*128) {
        int ic = i & 127, o = i >> 7;
        float wv = 0.f;
        if (o < 6)       wv = ldin(q16, o*128 + ic, sflags[18]);                // cls_w
        else if (o < 20) wv = ldin(q18, (o-6)*128 + ic, sflags[20]);            // reg_w
        else if (o < 24) wv = ldin(q20, (o-20)*128 + ic, sflags[22]);           // dir_w
        unsigned short hi = f2b(wv);
        whh[i] = hi;
        whl[i] = f2b(wv - b2f(hi));
    }
}

// ---------------- PFN + scatter, canvas NHWC bf16 [NY,NX,64] + occupancy mask ----------------
// LDS padded to 12 floats/point (48B, 16B-aligned) -> compute loop reads 3 aligned float4
// broadcasts per point (96 wave-level LDS ops vs 288 scalar broadcasts). Staging does
// distinct-address scalar writes (2 lanes/bank = free per m136).
__global__ __launch_bounds__(256) void pfn_scatter(
    const void* __restrict__ pillars, const int* __restrict__ coords,
    const void* __restrict__ pfn_w,
    const void* __restrict__ g, const void* __restrict__ bb,
    const void* __restrict__ m, const void* __restrict__ v,
    const int* __restrict__ flags, int b0,
    unsigned int* __restrict__ mask,
    unsigned short* __restrict__ canvas)
{
    __shared__ __align__(16) float lds[4][NPTS*12];   // 6,144 B padded
    const int wslot = threadIdx.x >> 6;
    const int lane  = threadIdx.x & 63;
    const int p = blockIdx.x * 4 + wslot;
    const int b = b0 + blockIdx.y;
    canvas += (size_t)blockIdx.y * CAN_STRIDE;
    mask   += (size_t)blockIdx.y * MASKW;
    const size_t pg = (size_t)b * NPIL + p;

    if (flags[0]) {
        const unsigned short* src = (const unsigned short*)pillars + pg * (NPTS*NCH);
        for (int idx = lane; idx < NPTS*NCH; idx += 64)
            lds[wslot][(idx/9)*12 + idx%9] = b2f(src[idx]);
    } else {
        const float4* src = (const float4*)((const float*)pillars + pg * (NPTS*NCH));
        for (int i = lane; i < (NPTS*NCH)/4; i += 64) {
            float4 d = src[i];
            const int e0 = 4*i;
            lds[wslot][((e0    )/9)*12 + (e0    )%9] = d.x;
            lds[wslot][((e0 + 1)/9)*12 + (e0 + 1)%9] = d.y;
            lds[wslot][((e0 + 2)/9)*12 + (e0 + 2)%9] = d.z;
            lds[wslot][((e0 + 3)/9)*12 + (e0 + 3)%9] = d.w;
        }
    }
    float w[NCH];
    const int fW = flags[3];
    #pragma unroll
    for (int c = 0; c < NCH; ++c) w[c] = ldin(pfn_w, lane*NCH + c, fW);
    float s = ldin(g, lane, flags[4]) / sqrtf(ldin(v, lane, flags[7]) + 1e-5f);
    float t = ldin(bb, lane, flags[5]) - ldin(m, lane, flags[6]) * s;
    __syncthreads();

    float mx = 0.0f;
    #pragma unroll 4
    for (int n = 0; n < NPTS; ++n) {
        const float4* r4 = (const float4*)&lds[wslot][n*12];
        float4 a0 = r4[0], a1 = r4[1], a2 = r4[2];
        float acc = a0.x * w[0];
        acc = fmaf(a0.y, w[1], acc);
        acc = fmaf(a0.z, w[2], acc);
        acc = fmaf(a0.w, w[3], acc);
        acc = fmaf(a1.x, w[4], acc);
        acc = fmaf(a1.y, w[5], acc);
        acc = fmaf(a1.z, w[6], acc);
        acc = fmaf(a1.w, w[7], acc);
        acc = fmaf(a2.x, w[8], acc);
        mx = fmaxf(mx, fmaxf(fmaf(acc, s, t), 0.0f));
    }
    const int cx = coords[pg*2], cy = coords[pg*2 + 1];
    if (cx + cy != 0 && cx >= 0 && cx < NXg && cy >= 0 && cy < NYg) {
        const int cell = cy*NXg + cx;
        canvas[(size_t)cell*64 + lane] = f2b(mx);
        if (lane == 0) atomicOr(&mask[cell >> 5], 1u << (cell & 31));
    }
}

// B-fragment loader for conv1 (direct from L2-resident wt1)
#define LDB1(buf, tap, ks) { \
    _Pragma("unroll") \
    for (int j_ = 0; j_ < 4; ++j_) \
        buf[j_] = *(const uint4*)&wt[((size_t)((tap)*64 + j_*16 + lr))*64 + (ks)*32 + lg*8]; \
}

// ---------------- conv1 (MFMA): canvas bf16 -> x1 bf16 [248,216,64], stride 2 ----------------
// r11-exact: odd/even row-sharing (stage 17 odd rows once -> 6 taps; restage 16 even rows
// -> 3 taps). LDS 71,808 B -> 2 blk/CU. DMA staging, mask-gated, 2-phase wt1 prefetch.
__global__ __launch_bounds__(256, 2) void conv1_mfma(
    const unsigned short* __restrict__ canvas,
    const unsigned int* __restrict__ mask,
    const unsigned short* __restrict__ wt,     // bf16 [9][64 oc][64 ic]
    const uint4* __restrict__ zbuf,
    const void* __restrict__ g, const void* __restrict__ bb,
    const void* __restrict__ m, const void* __restrict__ v,
    const int* __restrict__ flags,
    unsigned short* __restrict__ x1)
{
    __shared__ __align__(16) uint4 lin[17*33*8];   // 71,808 B
    const int tid = threadIdx.x;
    const int w = tid >> 6, l = tid & 63;
    const int lr = l & 15, lg = l >> 4;
    const int px0 = blockIdx.x * 16, oy0 = blockIdx.y * 16;
    canvas += (size_t)blockIdx.z * CAN_STRIDE;
    mask   += (size_t)blockIdx.z * MASKW;
    x1     += (size_t)blockIdx.z * X1_STRIDE;

    f32x4 acc[4][4];
    #pragma unroll
    for (int t = 0; t < 4; ++t)
        #pragma unroll
        for (int n = 0; n < 4; ++n) acc[t][n] = (f32x4){0.f,0.f,0.f,0.f};

    uint4 wbA[4], wbB[4];
    // phase-A tap order: (0,0),(2,0),(0,1),(2,1),(0,2),(2,2) -> taps {0,6,1,7,2,8}
    LDB1(wbA, 0, 0);

    // ---- phase A: stage 17 odd rows (iy = 2*oy0 - 1 + 2j) ----
    for (int q = tid; q < 17*33*8; q += 256) {
        int s = q & 7, t2 = q >> 3, c = t2 % 33, j = t2 / 33;
        int iy = 2*oy0 - 1 + 2*j, gx = 2*px0 - 1 + c;
        const void* src = zbuf;
        if ((unsigned)iy < (unsigned)NYg && (unsigned)gx < (unsigned)NXg) {
            const int cell = iy*NXg + gx;
            if ((mask[cell >> 5] >> (cell & 31)) & 1u)
                src = &canvas[(size_t)cell*64 + (s ^ ((c >> 1) & 7))*8];
        }
        async_load16(src, &lin[q]);
    }
    __syncthreads();                           // drains DMA
    {
        const int SEQA[6] = {0, 6, 1, 7, 2, 8};
        #pragma unroll
        for (int i = 0; i < 6; ++i) {
            const int tap = SEQA[i];
            const int kx = tap % 3;
            const int joff = (tap >= 6) ? 1 : 0;   // ky=2 reads odd row j=m+1
            const int c = 2*lr + kx;
            const int key = (c >> 1) & 7;
            LDB1(wbB, tap, 1);
            __builtin_amdgcn_s_setprio(1);
            #pragma unroll
            for (int t = 0; t < 4; ++t) {
                const int base = ((4*w + t + joff)*33 + c)*8;
                bf16x8 a0 = as_bf16x8(lin[base + (lg ^ key)]);
                #pragma unroll
                for (int n = 0; n < 4; ++n)
                    acc[t][n] = __builtin_amdgcn_mfma_f32_16x16x32_bf16(a0, as_bf16x8(wbA[n]), acc[t][n], 0, 0, 0);
            }
            __builtin_amdgcn_s_setprio(0);
            LDB1(wbA, (i < 5) ? SEQA[i + 1] : 3, 0);   // i=5 prefetches phase-B tap 3
            __builtin_amdgcn_s_setprio(1);
            #pragma unroll
            for (int t = 0; t < 4; ++t) {
                const int base = ((4*w + t + joff)*33 + c)*8;
                bf16x8 a1 = as_bf16x8(lin[base + ((4 + lg) ^ key)]);
                #pragma unroll
                for (int n = 0; n < 4; ++n)
                    acc[t][n] = __builtin_amdgcn_mfma_f32_16x16x32_bf16(a1, as_bf16x8(wbB[n]), acc[t][n], 0, 0, 0);
            }
            __builtin_amdgcn_s_setprio(0);
        }
    }

    // ---- phase B: stage 16 even rows (iy = 2*oy0 + 2j), compute ky=1 ----
    __syncthreads();                           // drain phase-A readers
    for (int q = tid; q < 16*33*8; q += 256) {
        int s = q & 7, t2 = q >> 3, c = t2 % 33, j = t2 / 33;
        int iy = 2*oy0 + 2*j, gx = 2*px0 - 1 + c;
        const void* src = zbuf;
        if ((unsigned)iy < (unsigned)NYg && (unsigned)gx < (unsigned)NXg) {
            const int cell = iy*NXg + gx;
            if ((mask[cell >> 5] >> (cell & 31)) & 1u)
                src = &canvas[(size_t)cell*64 + (s ^ ((c >> 1) & 7))*8];
        }
        async_load16(src, &lin[q]);
    }
    __syncthreads();
    #pragma unroll
    for (int tap = 3; tap < 6; ++tap) {        // ky=1, kx = tap-3
        const int kx = tap - 3;
        const int c = 2*lr + kx;
        const int key = (c >> 1) & 7;
        LDB1(wbB, tap, 1);
        __builtin_amdgcn_s_setprio(1);
        #pragma unroll
        for (int t = 0; t < 4; ++t) {
            const int base = ((4*w + t)*33 + c)*8;
            bf16x8 a0 = as_bf16x8(lin[base + (lg ^ key)]);
            #pragma unroll
            for (int n = 0; n < 4; ++n)
                acc[t][n] = __builtin_amdgcn_mfma_f32_16x16x32_bf16(a0, as_bf16x8(wbA[n]), acc[t][n], 0, 0, 0);
        }
        __builtin_amdgcn_s_setprio(0);
        if (tap < 5) LDB1(wbA, tap + 1, 0);
        __builtin_amdgcn_s_setprio(1);
        #pragma unroll
        for (int t = 0; t < 4; ++t) {
            const int base = ((4*w + t)*33 + c)*8;
            bf16x8 a1 = as_bf16x8(lin[base + ((4 + lg) ^ key)]);
            #pragma unroll
            for (int n = 0; n < 4; ++n)
                acc[t][n] = __builtin_amdgcn_mfma_f32_16x16x32_bf16(a1, as_bf16x8(wbB[n]), acc[t][n], 0, 0, 0);
        }
        __builtin_amdgcn_s_setprio(0);
    }

    float s[4], tt[4];
    #pragma unroll
    for (int n = 0; n < 4; ++n) {
        const int oc = n*16 + lr;
        s[n]  = ldin(g, oc, flags[9]) / sqrtf(ldin(v, oc, flags[12]) + 1e-5f);
        tt[n] = ldin(bb, oc, flags[10]) - ldin(m, oc, flags[11]) * s[n];
    }
    // D: col = lr = oc, row = lg*4+r = px
    #pragma unroll
    for (int t = 0; t < 4; ++t) {
        const int oy = oy0 + 4*w + t;
        if (oy >= OHh) continue;
        #pragma unroll
        for (int r = 0; r < 4; ++r) {
            const int px = px0 + lg*4 + r;
            if (px >= OWw) continue;
            unsigned short* orow = &x1[((size_t)oy*OWw + px)*64 + lr];
            #pragma unroll
            for (int n = 0; n < 4; ++n)
                orow[n*16] = f2b(fmaxf(fmaf(acc[t][n][r], s[n], tt[n]), 0.f));
        }
    }
}

// ---------------- conv2 (MFMA) + fused heads — r8/r10/r11-exact ----------------
__global__ __launch_bounds__(256, 2) void conv2_mfma(
    const unsigned short* __restrict__ x1,
    const unsigned short* __restrict__ wt,     // bf16 [9][128 oc][64 ic]
    const unsigned short* __restrict__ whh,    // bf16 [32 o][128 ic] head W hi
    const unsigned short* __restrict__ whl,    // bf16 [32 o][128 ic] head W lo
    const uint4* __restrict__ zbuf,
    const void* __restrict__ g, const void* __restrict__ bb,
    const void* __restrict__ m, const void* __restrict__ v,
    const void* __restrict__ cls_b, const void* __restrict__ reg_b, const void* __restrict__ dir_b,
    const int* __restrict__ flags, int b0,
    float* __restrict__ out)
{
    __shared__ __align__(16) char smem[74240];     // lin 41,472 | lw 32,768 ; P overlays 65,536
    uint4* lin = (uint4*)smem;
    uint4 (*lw)[128*8] = (uint4 (*)[128*8])(smem + 41472);
    unsigned short* P = (unsigned short*)smem;

    const int tid = threadIdx.x;
    const int w = tid >> 6, l = tid & 63;
    const int lr = l & 15, lg = l >> 4;
    const int px0 = blockIdx.x * 16, oy0 = blockIdx.y * 16;
    const int b = b0 + blockIdx.z;
    x1 += (size_t)blockIdx.z * X1_STRIDE;

    // stage lin via DMA (zero-stub for halo OOB)
    for (int q = tid; q < 18*18*8; q += 256) {
        int s = q & 7, t2 = q >> 3, c = t2 % 18, r = t2 / 18;
        int iy = oy0 - 1 + r, gx = px0 - 1 + c;
        const void* src = zbuf;
        if ((unsigned)iy < (unsigned)OHh && (unsigned)gx < (unsigned)OWw)
            src = &x1[((size_t)(iy*OWw + gx))*64 + (s ^ (c & 7))*8];
        async_load16(src, &lin[q]);
    }
    // stage lw[0] (tap 0) via DMA
    #pragma unroll
    for (int i = 0; i < 4; ++i) {
        const int q = tid + i*256, oc = q >> 3, s = q & 7;
        async_load16(&wt[((size_t)oc)*64 + (s ^ (oc & 7))*8], &lw[0][q]);
    }
    __syncthreads();

    f32x4 acc[4][8];
    #pragma unroll
    for (int t = 0; t < 4; ++t)
        #pragma unroll
        for (int n = 0; n < 8; ++n) acc[t][n] = (f32x4){0.f,0.f,0.f,0.f};

    #pragma unroll 1
    for (int tap = 0; tap < 9; ++tap) {
        const int ky = tap / 3, kx = tap - 3*ky;
        const int cur = tap & 1;
        if (tap < 8) {                          // DMA next tap's weights into the other buffer
            #pragma unroll
            for (int i = 0; i < 4; ++i) {
                const int q = tid + i*256, oc = q >> 3, s = q & 7;
                async_load16(&wt[((size_t)((tap+1)*128 + oc))*64 + (s ^ (oc & 7))*8],
                             &lw[cur ^ 1][q]);
            }
        }
        const int c = lr + kx;
        const int key = c & 7;
        bf16x8 af[4][2];
        #pragma unroll
        for (int t = 0; t < 4; ++t) {
            const int base = ((4*w + t + ky)*18 + c)*8;
            af[t][0] = as_bf16x8(lin[base + (lg ^ key)]);
            af[t][1] = as_bf16x8(lin[base + ((4 + lg) ^ key)]);
        }
        __builtin_amdgcn_s_setprio(1);
        #pragma unroll
        for (int n = 0; n < 8; ++n) {
            const int oc = n*16 + lr;
            const bf16x8 b0 = as_bf16x8(lw[cur][oc*8 + (lg ^ (oc & 7))]);
            const bf16x8 b1 = as_bf16x8(lw[cur][oc*8 + ((4 + lg) ^ (oc & 7))]);
            #pragma unroll
            for (int t = 0; t < 4; ++t) {
                acc[t][n] = __builtin_amdgcn_mfma_f32_16x16x32_bf16(af[t][0], b0, acc[t][n], 0, 0, 0);
                acc[t][n] = __builtin_amdgcn_mfma_f32_16x16x32_bf16(af[t][1], b1, acc[t][n], 0, 0, 0);
            }
        }
        __builtin_amdgcn_s_setprio(0);
        __syncthreads();                        // drains DMA; next tap's lw ready
    }

    float s[8], tt[8];
    #pragma unroll
    for (int n = 0; n < 8; ++n) {
        const int oc = n*16 + lr;
        s[n]  = ldin(g, oc, flags[14]) / sqrtf(ldin(v, oc, flags[17]) + 1e-5f);
        tt[n] = ldin(bb, oc, flags[15]) - ldin(m, oc, flags[16]) * s[n];
    }

    // ---- fused heads (r2-exact epilogue: pre-held hi/lo weights) ----
    float bias0, bias1;
    {
        int o = lr;
        bias0 = (o < 6) ? ldin(cls_b, o, flags[19]) : ldin(reg_b, o - 6, flags[21]);
        o = 16 + lr;
        bias1 = (o < 20) ? ldin(reg_b, o - 6, flags[21])
              : (o < 24) ? ldin(dir_b, o - 20, flags[23]) : 0.f;
    }
    uint4 wh[2][4], wl[2][4];
    #pragma unroll
    for (int n = 0; n < 2; ++n)
        #pragma unroll
        for (int ks = 0; ks < 4; ++ks) {
            const int ei = (n*16 + lr)*128 + ks*32 + lg*8;
            wh[n][ks] = *(const uint4*)&whh[ei];
            wl[n][ks] = *(const uint4*)&whl[ei];
        }

    __syncthreads();            // all waves done reading lin/lw before P overlay
    #pragma unroll
    for (int t = 0; t < 4; ++t) {
        const int pb = ((4*w + t)*16 + lg*4) * 128;
        #pragma unroll
        for (int n = 0; n < 8; ++n) {
            const int kk = 2*n + (lr >> 3), wi = lr & 7;
            #pragma unroll
            for (int r = 0; r < 4; ++r) {
                float val = fmaxf(fmaf(acc[t][n][r], s[n], tt[n]), 0.f);
                unsigned short h = f2b(val);
                P[pb + r*128 + ((kk ^ (lg*4 + r)) << 3) + wi] = h;
                acc[t][n][r] = val - b2f(h);
            }
        }
    }
    __syncthreads();

    f32x4 hacc[4][2];
    #pragma unroll
    for (int t = 0; t < 4; ++t) {
        hacc[t][0] = (f32x4){bias0, bias0, bias0, bias0};
        hacc[t][1] = (f32x4){bias1, bias1, bias1, bias1};
    }
    // pass 1: hi*Whi + hi*Wlo
    #pragma unroll
    for (int t = 0; t < 4; ++t) {
        const int mt = 4*w + t;
        bf16x8 pa[4];
        #pragma unroll
        for (int ks = 0; ks < 4; ++ks)
            pa[ks] = as_bf16x8(((const uint4*)P)[(mt*16 + lr)*16 + ((ks*4 + lg) ^ lr)]);
        #pragma unroll
        for (int n = 0; n < 2; ++n)
            #pragma unroll
            for (int ks = 0; ks < 4; ++ks) {
                hacc[t][n] = __builtin_amdgcn_mfma_f32_16x16x32_bf16(pa[ks], as_bf16x8(wh[n][ks]), hacc[t][n], 0, 0, 0);
                hacc[t][n] = __builtin_amdgcn_mfma_f32_16x16x32_bf16(pa[ks], as_bf16x8(wl[n][ks]), hacc[t][n], 0, 0, 0);
            }
    }
    __syncthreads();
    // fill P with lo
    #pragma unroll
    for (int t = 0; t < 4; ++t) {
        const int pb = ((4*w + t)*16 + lg*4) * 128;
        #pragma unroll
        for (int n = 0; n < 8; ++n) {
            const int kk = 2*n + (lr >> 3), wi = lr & 7;
            #pragma unroll
            for (int r = 0; r < 4; ++r)
                P[pb + r*128 + ((kk ^ (lg*4 + r)) << 3) + wi] = f2b(acc[t][n][r]);
        }
    }
    __syncthreads();
    // pass 2: lo*Whi
    #pragma unroll
    for (int t = 0; t < 4; ++t) {
        const int mt = 4*w + t;
        bf16x8 pa[4];
        #pragma unroll
        for (int ks = 0; ks < 4; ++ks)
            pa[ks] = as_bf16x8(((const uint4*)P)[(mt*16 + lr)*16 + ((ks*4 + lg) ^ lr)]);
        #pragma unroll
        for (int n = 0; n < 2; ++n)
            #pragma unroll
            for (int ks = 0; ks < 4; ++ks)
                hacc[t][n] = __builtin_amdgcn_mfma_f32_16x16x32_bf16(pa[ks], as_bf16x8(wh[n][ks]), hacc[t][n], 0, 0, 0);
    }

    const size_t regbase = (size_t)BATCH*6*HWp;
    const size_t dirbase = regbase + (size_t)BATCH*14*HWp;
    const int pxw = px0 + lg*4;
    #pragma unroll
    for (int n = 0; n < 2; ++n) {
        const int o = n*16 + lr;
        float* plane;
        bool valid = (pxw < OWw);
        if (o < 6)       plane = out + ((size_t)b*6 + o)*HWp;
        else if (o < 20) plane = out + regbase + ((size_t)b*14 + (o - 6))*HWp;
        else if (o < 24) plane = out + dirbase + ((size_t)b*4 + (o - 20))*HWp;
        else valid = false;
        if (!valid) continue;
        #pragma unroll
        for (int t = 0; t < 4; ++t) {
            const int oy = oy0 + 4*w + t;
            if (oy < OHh)
                *(float4*)&plane[(size_t)oy*OWw + pxw] = *(float4*)&hacc[t][n];
        }
    }
}

extern "C" void kernel_launch(void* const* d_in, const int* in_sizes, int n_in,
                              void* d_out, int out_size, void* d_ws, size_t ws_size,
                              hipStream_t stream) {
    static const int EXPECT[24] = {13824000,96000,48000,576,64,64,64,64,36864,
                                   64,64,64,64,73728,128,128,128,128,768,6,1792,14,512,4};
    const void* din[24];
    {
        bool used[24] = {false};
        int perm[24];
        bool ok = (n_in >= 24);
        if (ok) {
            for (int j = 0; j < 24 && ok; ++j) {
                perm[j] = -1;
                for (int i = 0; i < 24; ++i)
                    if (!used[i] && in_sizes[i] == EXPECT[j]) { perm[j] = i; used[i] = true; break; }
                if (perm[j] < 0) ok = false;
            }
        }
        for (int j = 0; j < 24; ++j) din[j] = d_in[ok ? perm[j] : j];
        if (!ok) {
            sentinel_kernel<<<1, 64, 0, stream>>>((float*)d_out, 13000.0f + n_in);
            return;
        }
    }
    const int* coords = (const int*)din[1];
    float* out = (float*)d_out;

    // layout: flags 256 | wt1 73,728 | wt2 147,456 | whh 8,192 | whl 8,192 | zbuf 64 |
    //         mask (ALWAYS 4 x 32,768 -> no memsets in either path) |
    //         x1 bf16 (nb x 6,856,704) | canvas bf16 (nb x 27,426,816)
    const size_t X1B   = (size_t)HWp*64*2;          // 6,856,704
    const size_t CANB  = (size_t)NYg*NXg*64*2;      // 27,426,816
    const size_t MASKB = (size_t)MASKW*4;           // 32,768 per batch
    const size_t ZOFF  = 256 + 73728 + 147456 + 8192 + 8192;   // 237,824
    const size_t BASE  = ZOFF + 64;                 // 237,888
    const size_t NEED1 = BASE + 4*MASKB + X1B + CANB;
    const size_t NEED4 = BASE + 4*MASKB + 4*(X1B + CANB);
    if (ws_size < NEED1) {
        sentinel_kernel<<<1, 64, 0, stream>>>(out, 10000.0f + (float)(ws_size >> 20));
        return;
    }
    const int nb = (ws_size >= NEED4) ? 4 : 1;
    char* ws = (char*)d_ws;
    int* flags = (int*)ws;
    unsigned short* wt1 = (unsigned short*)(ws + 256);
    unsigned short* wt2 = (unsigned short*)(ws + 256 + 73728);
    unsigned short* whh = (unsigned short*)(ws + 256 + 73728 + 147456);
    unsigned short* whl = (unsigned short*)(ws + 256 + 73728 + 147456 + 8192);
    unsigned int*   zbuf = (unsigned int*)(ws + ZOFF);
    unsigned int*   maskbuf = (unsigned int*)(ws + BASE);
    unsigned short* x1  = (unsigned short*)(ws + BASE + 4*MASKB);
    unsigned short* canvas = (unsigned short*)(ws + BASE + 4*MASKB + (size_t)nb*X1B);

    prep_weights<<<288, 256, 0, stream>>>(
        din[0], din[3], din[4], din[5], din[6], din[7],
        din[8], din[9], din[10], din[11], din[12],
        din[13], din[14], din[15], din[16], din[17],
        din[18], din[19], din[20], din[21], din[22], din[23],
        wt1, wt2, whh, whl, maskbuf, 4*MASKW, zbuf, flags);

    if (nb == 4) {
        pfn_scatter<<<dim3(NPIL/4, 4), 256, 0, stream>>>(
            din[0], coords, din[3], din[4], din[5], din[6], din[7], flags, 0, maskbuf, canvas);
        conv1_mfma<<<dim3(14, 16, 4), 256, 0, stream>>>(
            canvas, maskbuf, wt1, (const uint4*)zbuf,
            din[9], din[10], din[11], din[12], flags, x1);
        conv2_mfma<<<dim3(14, 16, 4), 256, 0, stream>>>(
            x1, wt2, whh, whl, (const uint4*)zbuf, din[14], din[15], din[16], din[17],
            din[19], din[21], din[23], flags, 0, out);
    } else {
        for (int b = 0; b < BATCH; ++b) {
            unsigned int* mb = maskbuf + (size_t)b * MASKW;   // per-batch mask, pre-zeroed
            pfn_scatter<<<dim3(NPIL/4, 1), 256, 0, stream>>>(
                din[0], coords, din[3], din[4], din[5], din[6], din[7], flags, b, mb, canvas);
            conv1_mfma<<<dim3(14, 16, 1), 256, 0, stream>>>(
                canvas, mb, wt1, (const uint4*)zbuf,
                din[9], din[10], din[11], din[12], flags, x1);
            conv2_mfma<<<dim3(14, 16, 1), 256, 0, stream>>>(
                x1, wt2, whh, whl, (const uint4*)zbuf, din[14], din[15], din[16], din[17],
                din[19], din[21], din[23], flags, b, out);
        }
    }
}

// Round 13
// 307.541 us; speedup vs baseline: 1.1522x; 1.0445x over previous
//
#include <hip/hip_runtime.h>

// ---------------- constants ----------------
#define BATCH 4
#define NPIL 12000
#define NPTS 32
#define NCH 9
#define NXg 432
#define NYg 496
#define OHh 248
#define OWw 216
#define HWp (OHh*OWw)          // 53568
#define CAN_STRIDE ((size_t)NYg*NXg*64)      // ushort elems (bf16 canvas)
#define X1_STRIDE  ((size_t)OHh*OWw*64)      // ushort elems (bf16 x1)
#define MASKW 8192                            // mask words per batch (padded)

typedef __bf16 bf16x8 __attribute__((ext_vector_type(8)));
typedef float  f32x4  __attribute__((ext_vector_type(4)));

__device__ __forceinline__ bf16x8 as_bf16x8(uint4 u) {
    union { uint4 u; bf16x8 b; } c; c.u = u; return c.b;
}

__device__ __forceinline__ float b2f(unsigned int u) {
    union { unsigned int i; float f; } x; x.i = (u & 0xffffu) << 16; return x.f;
}
__device__ __forceinline__ unsigned short f2b(float f) {
    union { float f; unsigned int i; } x; x.f = f;
    unsigned int r = x.i + 0x7fffu + ((x.i >> 16) & 1u);   // RNE
    return (unsigned short)(r >> 16);
}
__device__ __forceinline__ float ldin(const void* p, int i, int isbf) {
    return isbf ? b2f(((const unsigned short*)p)[i]) : ((const float*)p)[i];
}

// async global->LDS DMA, 16B per lane. LDS dest must be (wave-uniform base + lane*16);
// global source may be fully per-lane (m173 pattern: swizzle lives on the SOURCE address).
__device__ __forceinline__ void async_load16(const void* gsrc, void* ldst) {
    __builtin_amdgcn_global_load_lds(
        (const __attribute__((address_space(1))) unsigned char*)gsrc,
        (__attribute__((address_space(3))) unsigned char*)ldst, 16, 0, 0);
}

__global__ void sentinel_kernel(float* out, float val) {
    if (threadIdx.x == 0) out[0] = val;
}

// ---------------- dtype plausibility (robustness; all fp32 in practice) ----------------
__device__ __forceinline__ int plaus16(unsigned short h) {
    if ((h & 0x7fffu) == 0) return 1;
    unsigned e = (h >> 7) & 0xffu;
    return (e >= 106 && e <= 132) ? 1 : 0;
}

// ---------------- weight prep + integrated per-block dtype detection ----------------
__global__ __launch_bounds__(256) void prep_weights(
    const void* q0,  const void* q1,  const void* q2,  const void* q3,
    const void* q4,  const void* q5,  const void* q6,  const void* q7,
    const void* q8,  const void* q9,  const void* q10, const void* q11,
    const void* q12, const void* q13, const void* q14, const void* q15,
    const void* q16, const void* q17, const void* q18, const void* q19,
    const void* q20, const void* q21,
    unsigned short* __restrict__ wt1, unsigned short* __restrict__ wt2,
    unsigned short* __restrict__ whh, unsigned short* __restrict__ whl,
    unsigned int* __restrict__ mask, int mask_words,
    unsigned int* __restrict__ zbuf,
    int* __restrict__ flags_out)
{
    __shared__ int votes[22];
    __shared__ int sflags[24];
    const void* ptrs[22] = {q0,q1,q2,q3,q4,q5,q6,q7,q8,q9,q10,q11,
                            q12,q13,q14,q15,q16,q17,q18,q19,q20,q21};
    const int Ks[22]   = {64,64,32,32,32,32,64,32,32,32,32,64,64,64,64,64,64,3,64,7,64,2};
    const int didx[22] = {0,3,4,5,6,7,8,9,10,11,12,13,14,15,16,17,18,19,20,21,22,23};
    const int tid = threadIdx.x;
    if (tid < 22) votes[tid] = 0;
    if (tid < 24) sflags[tid] = 0;
    __syncthreads();
    #pragma unroll 1
    for (int wb = 0; wb < 4; ++wb) {          // 4 windows cover cumulative offset space (972)
        const int vt = wb*256 + tid;
        int off = 0;
        #pragma unroll                         // full unroll -> constant ptrs[] indices (SGPR)
        for (int t = 0; t < 22; ++t) {
            if (vt >= off && vt < off + Ks[t]) {
                unsigned w = ((const unsigned*)ptrs[t])[vt - off];
                if (plaus16((unsigned short)w) && plaus16((unsigned short)(w >> 16)))
                    atomicAdd(&votes[t], 1);
            }
            off += Ks[t];
        }
    }
    __syncthreads();
    if (tid < 22) {
        int isbf;
        if (tid == 17 || tid == 19 || tid == 21) {
            int pv = votes[17] + votes[19] + votes[21];
            isbf = (pv * 4 >= 3 * 12);
        } else {
            isbf = (votes[tid] * 4 >= 3 * Ks[tid]);
        }
        sflags[didx[tid]] = isbf;
    }
    __syncthreads();
    if (blockIdx.x == 0 && tid < 24) flags_out[tid] = sflags[tid];

    const int f1 = sflags[8], f2 = sflags[13];
    int i = blockIdx.x * 256 + tid;
    if (i < mask_words) mask[i] = 0u;
    if (i < 16) zbuf[i] = 0u;
    if (i < 64*64*9) {
        int kx = i % 3; int t = i / 3; int ky = t % 3; t /= 3; int ic = t % 64; int oc = t / 64;
        wt1[((size_t)(ky*3 + kx)*64 + oc)*64 + ic] = f2b(ldin(q6, i, f1));      // q6 = w1
    }
    if (i < 128*64*9) {
        int kx = i % 3; int t = i / 3; int ky = t % 3; t /= 3; int ic = t % 64; int oc = t / 64;
        wt2[((size_t)(ky*3 + kx)*128 + oc)*64 + ic] = f2b(ldin(q11, i, f2));    // q11 = w2
    }
    if (i < 32*128) {
        int ic = i & 127, o = i >> 7;
        float wv = 0.f;
        if (o < 6)       wv = ldin(q16, o*128 + ic, sflags[18]);                // cls_w
        else if (o < 20) wv = ldin(q18, (o-6)*128 + ic, sflags[20]);            // reg_w
        else if (o < 24) wv = ldin(q20, (o-20)*128 + ic, sflags[22]);           // dir_w
        unsigned short hi = f2b(wv);
        whh[i] = hi;
        whl[i] = f2b(wv - b2f(hi));
    }
}

// ---------------- PFN + scatter, canvas NHWC bf16 [NY,NX,64] + occupancy mask ----------------
// LDS padded to 12 floats/point -> compute loop reads 3 aligned float4 broadcasts per point.
__global__ __launch_bounds__(256) void pfn_scatter(
    const void* __restrict__ pillars, const int* __restrict__ coords,
    const void* __restrict__ pfn_w,
    const void* __restrict__ g, const void* __restrict__ bb,
    const void* __restrict__ m, const void* __restrict__ v,
    const int* __restrict__ flags, int b0,
    unsigned int* __restrict__ mask,
    unsigned short* __restrict__ canvas)
{
    __shared__ __align__(16) float lds[4][NPTS*12];   // 6,144 B padded
    const int wslot = threadIdx.x >> 6;
    const int lane  = threadIdx.x & 63;
    const int p = blockIdx.x * 4 + wslot;
    const int b = b0 + blockIdx.y;
    canvas += (size_t)blockIdx.y * CAN_STRIDE;
    mask   += (size_t)blockIdx.y * MASKW;
    const size_t pg = (size_t)b * NPIL + p;

    if (flags[0]) {
        const unsigned short* src = (const unsigned short*)pillars + pg * (NPTS*NCH);
        for (int idx = lane; idx < NPTS*NCH; idx += 64)
            lds[wslot][(idx/9)*12 + idx%9] = b2f(src[idx]);
    } else {
        const float4* src = (const float4*)((const float*)pillars + pg * (NPTS*NCH));
        for (int i = lane; i < (NPTS*NCH)/4; i += 64) {
            float4 d = src[i];
            const int e0 = 4*i;
            lds[wslot][((e0    )/9)*12 + (e0    )%9] = d.x;
            lds[wslot][((e0 + 1)/9)*12 + (e0 + 1)%9] = d.y;
            lds[wslot][((e0 + 2)/9)*12 + (e0 + 2)%9] = d.z;
            lds[wslot][((e0 + 3)/9)*12 + (e0 + 3)%9] = d.w;
        }
    }
    float w[NCH];
    const int fW = flags[3];
    #pragma unroll
    for (int c = 0; c < NCH; ++c) w[c] = ldin(pfn_w, lane*NCH + c, fW);
    float s = ldin(g, lane, flags[4]) / sqrtf(ldin(v, lane, flags[7]) + 1e-5f);
    float t = ldin(bb, lane, flags[5]) - ldin(m, lane, flags[6]) * s;
    __syncthreads();

    float mx = 0.0f;
    #pragma unroll 4
    for (int n = 0; n < NPTS; ++n) {
        const float4* r4 = (const float4*)&lds[wslot][n*12];
        float4 a0 = r4[0], a1 = r4[1], a2 = r4[2];
        float acc = a0.x * w[0];
        acc = fmaf(a0.y, w[1], acc);
        acc = fmaf(a0.z, w[2], acc);
        acc = fmaf(a0.w, w[3], acc);
        acc = fmaf(a1.x, w[4], acc);
        acc = fmaf(a1.y, w[5], acc);
        acc = fmaf(a1.z, w[6], acc);
        acc = fmaf(a1.w, w[7], acc);
        acc = fmaf(a2.x, w[8], acc);
        mx = fmaxf(mx, fmaxf(fmaf(acc, s, t), 0.0f));
    }
    const int cx = coords[pg*2], cy = coords[pg*2 + 1];
    if (cx + cy != 0 && cx >= 0 && cx < NXg && cy >= 0 && cy < NYg) {
        const int cell = cy*NXg + cx;
        canvas[(size_t)cell*64 + lane] = f2b(mx);
        if (lane == 0) atomicOr(&mask[cell >> 5], 1u << (cell & 31));
    }
}

// B-fragment loader for conv1 (direct from L2-resident wt1)
#define LDB1(buf, tap, ks) { \
    _Pragma("unroll") \
    for (int j_ = 0; j_ < 4; ++j_) \
        buf[j_] = *(const uint4*)&wt[((size_t)((tap)*64 + j_*16 + lr))*64 + (ks)*32 + lg*8]; \
}

// ---------------- conv1 (MFMA): canvas bf16 -> x1 bf16 [248,216,64], stride 2 ----------------
// r11 structure (odd/even row-sharing) + NEW: per-phase mask-word precache in LDS.
// Staging's ~8.7K global mask loads (8 chunks/cell redundant) become LDS reads: each halo
// row's <=3 mask words + base word index cached by <=51 threads, 1 extra barrier per phase.
__global__ __launch_bounds__(256, 2) void conv1_mfma(
    const unsigned short* __restrict__ canvas,
    const unsigned int* __restrict__ mask,
    const unsigned short* __restrict__ wt,     // bf16 [9][64 oc][64 ic]
    const uint4* __restrict__ zbuf,
    const void* __restrict__ g, const void* __restrict__ bb,
    const void* __restrict__ m, const void* __restrict__ v,
    const int* __restrict__ flags,
    unsigned short* __restrict__ x1)
{
    __shared__ __align__(16) uint4 lin[17*33*8];   // 71,808 B
    __shared__ int smask[17*4];                    // {3 words, base} per halo row (+272 B)
    const int tid = threadIdx.x;
    const int w = tid >> 6, l = tid & 63;
    const int lr = l & 15, lg = l >> 4;
    const int px0 = blockIdx.x * 16, oy0 = blockIdx.y * 16;
    canvas += (size_t)blockIdx.z * CAN_STRIDE;
    mask   += (size_t)blockIdx.z * MASKW;
    x1     += (size_t)blockIdx.z * X1_STRIDE;

    const int gxb = (2*px0 - 1 < 0) ? 0 : 2*px0 - 1;   // clamped halo start (for word base)

    f32x4 acc[4][4];
    #pragma unroll
    for (int t = 0; t < 4; ++t)
        #pragma unroll
        for (int n = 0; n < 4; ++n) acc[t][n] = (f32x4){0.f,0.f,0.f,0.f};

    uint4 wbA[4], wbB[4];
    // phase-A tap order: (0,0),(2,0),(0,1),(2,1),(0,2),(2,2) -> taps {0,6,1,7,2,8}
    LDB1(wbA, 0, 0);

    // ---- phase A: precache mask rows, stage 17 odd rows (iy = 2*oy0 - 1 + 2j) ----
    if (tid < 17*3) {
        const int j = tid / 3, wo = tid % 3;
        const int iy = 2*oy0 - 1 + 2*j;
        const int bw = (iy*NXg + gxb) >> 5;
        unsigned wv = 0u;
        if ((unsigned)iy < (unsigned)NYg) wv = mask[bw + wo];
        smask[j*4 + wo] = (int)wv;
        if (wo == 0) smask[j*4 + 3] = bw;
    }
    __syncthreads();
    for (int q = tid; q < 17*33*8; q += 256) {
        int s = q & 7, t2 = q >> 3, c = t2 % 33, j = t2 / 33;
        int iy = 2*oy0 - 1 + 2*j, gx = 2*px0 - 1 + c;
        const void* src = zbuf;
        if ((unsigned)iy < (unsigned)NYg && (unsigned)gx < (unsigned)NXg) {
            const int cell = iy*NXg + gx;
            const int wr = (cell >> 5) - smask[j*4 + 3];
            if ((smask[j*4 + wr] >> (cell & 31)) & 1)
                src = &canvas[(size_t)cell*64 + (s ^ ((c >> 1) & 7))*8];
        }
        async_load16(src, &lin[q]);
    }
    __syncthreads();                           // drains DMA
    {
        const int SEQA[6] = {0, 6, 1, 7, 2, 8};
        #pragma unroll
        for (int i = 0; i < 6; ++i) {
            const int tap = SEQA[i];
            const int kx = tap % 3;
            const int joff = (tap >= 6) ? 1 : 0;   // ky=2 reads odd row j=m+1
            const int c = 2*lr + kx;
            const int key = (c >> 1) & 7;
            LDB1(wbB, tap, 1);
            __builtin_amdgcn_s_setprio(1);
            #pragma unroll
            for (int t = 0; t < 4; ++t) {
                const int base = ((4*w + t + joff)*33 + c)*8;
                bf16x8 a0 = as_bf16x8(lin[base + (lg ^ key)]);
                #pragma unroll
                for (int n = 0; n < 4; ++n)
                    acc[t][n] = __builtin_amdgcn_mfma_f32_16x16x32_bf16(a0, as_bf16x8(wbA[n]), acc[t][n], 0, 0, 0);
            }
            __builtin_amdgcn_s_setprio(0);
            LDB1(wbA, (i < 5) ? SEQA[i + 1] : 3, 0);   // i=5 prefetches phase-B tap 3
            __builtin_amdgcn_s_setprio(1);
            #pragma unroll
            for (int t = 0; t < 4; ++t) {
                const int base = ((4*w + t + joff)*33 + c)*8;
                bf16x8 a1 = as_bf16x8(lin[base + ((4 + lg) ^ key)]);
                #pragma unroll
                for (int n = 0; n < 4; ++n)
                    acc[t][n] = __builtin_amdgcn_mfma_f32_16x16x32_bf16(a1, as_bf16x8(wbB[n]), acc[t][n], 0, 0, 0);
            }
            __builtin_amdgcn_s_setprio(0);
        }
    }

    // ---- phase B: precache, stage 16 even rows (iy = 2*oy0 + 2j), compute ky=1 ----
    __syncthreads();                           // drain phase-A readers
    if (tid < 16*3) {
        const int j = tid / 3, wo = tid % 3;
        const int iy = 2*oy0 + 2*j;
        const int bw = (iy*NXg + gxb) >> 5;
        unsigned wv = 0u;
        if ((unsigned)iy < (unsigned)NYg) wv = mask[bw + wo];
        smask[j*4 + wo] = (int)wv;
        if (wo == 0) smask[j*4 + 3] = bw;
    }
    __syncthreads();
    for (int q = tid; q < 16*33*8; q += 256) {
        int s = q & 7, t2 = q >> 3, c = t2 % 33, j = t2 / 33;
        int iy = 2*oy0 + 2*j, gx = 2*px0 - 1 + c;
        const void* src = zbuf;
        if ((unsigned)iy < (unsigned)NYg && (unsigned)gx < (unsigned)NXg) {
            const int cell = iy*NXg + gx;
            const int wr = (cell >> 5) - smask[j*4 + 3];
            if ((smask[j*4 + wr] >> (cell & 31)) & 1)
                src = &canvas[(size_t)cell*64 + (s ^ ((c >> 1) & 7))*8];
        }
        async_load16(src, &lin[q]);
    }
    __syncthreads();
    #pragma unroll
    for (int tap = 3; tap < 6; ++tap) {        // ky=1, kx = tap-3
        const int kx = tap - 3;
        const int c = 2*lr + kx;
        const int key = (c >> 1) & 7;
        LDB1(wbB, tap, 1);
        __builtin_amdgcn_s_setprio(1);
        #pragma unroll
        for (int t = 0; t < 4; ++t) {
            const int base = ((4*w + t)*33 + c)*8;
            bf16x8 a0 = as_bf16x8(lin[base + (lg ^ key)]);
            #pragma unroll
            for (int n = 0; n < 4; ++n)
                acc[t][n] = __builtin_amdgcn_mfma_f32_16x16x32_bf16(a0, as_bf16x8(wbA[n]), acc[t][n], 0, 0, 0);
        }
        __builtin_amdgcn_s_setprio(0);
        if (tap < 5) LDB1(wbA, tap + 1, 0);
        __builtin_amdgcn_s_setprio(1);
        #pragma unroll
        for (int t = 0; t < 4; ++t) {
            const int base = ((4*w + t)*33 + c)*8;
            bf16x8 a1 = as_bf16x8(lin[base + ((4 + lg) ^ key)]);
            #pragma unroll
            for (int n = 0; n < 4; ++n)
                acc[t][n] = __builtin_amdgcn_mfma_f32_16x16x32_bf16(a1, as_bf16x8(wbB[n]), acc[t][n], 0, 0, 0);
        }
        __builtin_amdgcn_s_setprio(0);
    }

    float s[4], tt[4];
    #pragma unroll
    for (int n = 0; n < 4; ++n) {
        const int oc = n*16 + lr;
        s[n]  = ldin(g, oc, flags[9]) / sqrtf(ldin(v, oc, flags[12]) + 1e-5f);
        tt[n] = ldin(bb, oc, flags[10]) - ldin(m, oc, flags[11]) * s[n];
    }
    // D: col = lr = oc, row = lg*4+r = px
    #pragma unroll
    for (int t = 0; t < 4; ++t) {
        const int oy = oy0 + 4*w + t;
        if (oy >= OHh) continue;
        #pragma unroll
        for (int r = 0; r < 4; ++r) {
            const int px = px0 + lg*4 + r;
            if (px >= OWw) continue;
            unsigned short* orow = &x1[((size_t)oy*OWw + px)*64 + lr];
            #pragma unroll
            for (int n = 0; n < 4; ++n)
                orow[n*16] = f2b(fmaxf(fmaf(acc[t][n][r], s[n], tt[n]), 0.f));
        }
    }
}

// ---------------- conv2 (MFMA) + fused heads — r8/r10/r11/r12-exact ----------------
__global__ __launch_bounds__(256, 2) void conv2_mfma(
    const unsigned short* __restrict__ x1,
    const unsigned short* __restrict__ wt,     // bf16 [9][128 oc][64 ic]
    const unsigned short* __restrict__ whh,    // bf16 [32 o][128 ic] head W hi
    const unsigned short* __restrict__ whl,    // bf16 [32 o][128 ic] head W lo
    const uint4* __restrict__ zbuf,
    const void* __restrict__ g, const void* __restrict__ bb,
    const void* __restrict__ m, const void* __restrict__ v,
    const void* __restrict__ cls_b, const void* __restrict__ reg_b, const void* __restrict__ dir_b,
    const int* __restrict__ flags, int b0,
    float* __restrict__ out)
{
    __shared__ __align__(16) char smem[74240];     // lin 41,472 | lw 32,768 ; P overlays 65,536
    uint4* lin = (uint4*)smem;
    uint4 (*lw)[128*8] = (uint4 (*)[128*8])(smem + 41472);
    unsigned short* P = (unsigned short*)smem;

    const int tid = threadIdx.x;
    const int w = tid >> 6, l = tid & 63;
    const int lr = l & 15, lg = l >> 4;
    const int px0 = blockIdx.x * 16, oy0 = blockIdx.y * 16;
    const int b = b0 + blockIdx.z;
    x1 += (size_t)blockIdx.z * X1_STRIDE;

    // stage lin via DMA (zero-stub for halo OOB)
    for (int q = tid; q < 18*18*8; q += 256) {
        int s = q & 7, t2 = q >> 3, c = t2 % 18, r = t2 / 18;
        int iy = oy0 - 1 + r, gx = px0 - 1 + c;
        const void* src = zbuf;
        if ((unsigned)iy < (unsigned)OHh && (unsigned)gx < (unsigned)OWw)
            src = &x1[((size_t)(iy*OWw + gx))*64 + (s ^ (c & 7))*8];
        async_load16(src, &lin[q]);
    }
    // stage lw[0] (tap 0) via DMA
    #pragma unroll
    for (int i = 0; i < 4; ++i) {
        const int q = tid + i*256, oc = q >> 3, s = q & 7;
        async_load16(&wt[((size_t)oc)*64 + (s ^ (oc & 7))*8], &lw[0][q]);
    }
    __syncthreads();

    f32x4 acc[4][8];
    #pragma unroll
    for (int t = 0; t < 4; ++t)
        #pragma unroll
        for (int n = 0; n < 8; ++n) acc[t][n] = (f32x4){0.f,0.f,0.f,0.f};

    #pragma unroll 1
    for (int tap = 0; tap < 9; ++tap) {
        const int ky = tap / 3, kx = tap - 3*ky;
        const int cur = tap & 1;
        if (tap < 8) {                          // DMA next tap's weights into the other buffer
            #pragma unroll
            for (int i = 0; i < 4; ++i) {
                const int q = tid + i*256, oc = q >> 3, s = q & 7;
                async_load16(&wt[((size_t)((tap+1)*128 + oc))*64 + (s ^ (oc & 7))*8],
                             &lw[cur ^ 1][q]);
            }
        }
        const int c = lr + kx;
        const int key = c & 7;
        bf16x8 af[4][2];
        #pragma unroll
        for (int t = 0; t < 4; ++t) {
            const int base = ((4*w + t + ky)*18 + c)*8;
            af[t][0] = as_bf16x8(lin[base + (lg ^ key)]);
            af[t][1] = as_bf16x8(lin[base + ((4 + lg) ^ key)]);
        }
        __builtin_amdgcn_s_setprio(1);
        #pragma unroll
        for (int n = 0; n < 8; ++n) {
            const int oc = n*16 + lr;
            const bf16x8 b0 = as_bf16x8(lw[cur][oc*8 + (lg ^ (oc & 7))]);
            const bf16x8 b1 = as_bf16x8(lw[cur][oc*8 + ((4 + lg) ^ (oc & 7))]);
            #pragma unroll
            for (int t = 0; t < 4; ++t) {
                acc[t][n] = __builtin_amdgcn_mfma_f32_16x16x32_bf16(af[t][0], b0, acc[t][n], 0, 0, 0);
                acc[t][n] = __builtin_amdgcn_mfma_f32_16x16x32_bf16(af[t][1], b1, acc[t][n], 0, 0, 0);
            }
        }
        __builtin_amdgcn_s_setprio(0);
        __syncthreads();                        // drains DMA; next tap's lw ready
    }

    float s[8], tt[8];
    #pragma unroll
    for (int n = 0; n < 8; ++n) {
        const int oc = n*16 + lr;
        s[n]  = ldin(g, oc, flags[14]) / sqrtf(ldin(v, oc, flags[17]) + 1e-5f);
        tt[n] = ldin(bb, oc, flags[15]) - ldin(m, oc, flags[16]) * s[n];
    }

    // ---- fused heads (r2-exact epilogue: pre-held hi/lo weights) ----
    float bias0, bias1;
    {
        int o = lr;
        bias0 = (o < 6) ? ldin(cls_b, o, flags[19]) : ldin(reg_b, o - 6, flags[21]);
        o = 16 + lr;
        bias1 = (o < 20) ? ldin(reg_b, o - 6, flags[21])
              : (o < 24) ? ldin(dir_b, o - 20, flags[23]) : 0.f;
    }
    uint4 wh[2][4], wl[2][4];
    #pragma unroll
    for (int n = 0; n < 2; ++n)
        #pragma unroll
        for (int ks = 0; ks < 4; ++ks) {
            const int ei = (n*16 + lr)*128 + ks*32 + lg*8;
            wh[n][ks] = *(const uint4*)&whh[ei];
            wl[n][ks] = *(const uint4*)&whl[ei];
        }

    __syncthreads();            // all waves done reading lin/lw before P overlay
    #pragma unroll
    for (int t = 0; t < 4; ++t) {
        const int pb = ((4*w + t)*16 + lg*4) * 128;
        #pragma unroll
        for (int n = 0; n < 8; ++n) {
            const int kk = 2*n + (lr >> 3), wi = lr & 7;
            #pragma unroll
            for (int r = 0; r < 4; ++r) {
                float val = fmaxf(fmaf(acc[t][n][r], s[n], tt[n]), 0.f);
                unsigned short h = f2b(val);
                P[pb + r*128 + ((kk ^ (lg*4 + r)) << 3) + wi] = h;
                acc[t][n][r] = val - b2f(h);
            }
        }
    }
    __syncthreads();

    f32x4 hacc[4][2];
    #pragma unroll
    for (int t = 0; t < 4; ++t) {
        hacc[t][0] = (f32x4){bias0, bias0, bias0, bias0};
        hacc[t][1] = (f32x4){bias1, bias1, bias1, bias1};
    }
    // pass 1: hi*Whi + hi*Wlo
    #pragma unroll
    for (int t = 0; t < 4; ++t) {
        const int mt = 4*w + t;
        bf16x8 pa[4];
        #pragma unroll
        for (int ks = 0; ks < 4; ++ks)
            pa[ks] = as_bf16x8(((const uint4*)P)[(mt*16 + lr)*16 + ((ks*4 + lg) ^ lr)]);
        #pragma unroll
        for (int n = 0; n < 2; ++n)
            #pragma unroll
            for (int ks = 0; ks < 4; ++ks) {
                hacc[t][n] = __builtin_amdgcn_mfma_f32_16x16x32_bf16(pa[ks], as_bf16x8(wh[n][ks]), hacc[t][n], 0, 0, 0);
                hacc[t][n] = __builtin_amdgcn_mfma_f32_16x16x32_bf16(pa[ks], as_bf16x8(wl[n][ks]), hacc[t][n], 0, 0, 0);
            }
    }
    __syncthreads();
    // fill P with lo
    #pragma unroll
    for (int t = 0; t < 4; ++t) {
        const int pb = ((4*w + t)*16 + lg*4) * 128;
        #pragma unroll
        for (int n = 0; n < 8; ++n) {
            const int kk = 2*n + (lr >> 3), wi = lr & 7;
            #pragma unroll
            for (int r = 0; r < 4; ++r)
                P[pb + r*128 + ((kk ^ (lg*4 + r)) << 3) + wi] = f2b(acc[t][n][r]);
        }
    }
    __syncthreads();
    // pass 2: lo*Whi
    #pragma unroll
    for (int t = 0; t < 4; ++t) {
        const int mt = 4*w + t;
        bf16x8 pa[4];
        #pragma unroll
        for (int ks = 0; ks < 4; ++ks)
            pa[ks] = as_bf16x8(((const uint4*)P)[(mt*16 + lr)*16 + ((ks*4 + lg) ^ lr)]);
        #pragma unroll
        for (int n = 0; n < 2; ++n)
            #pragma unroll
            for (int ks = 0; ks < 4; ++ks)
                hacc[t][n] = __builtin_amdgcn_mfma_f32_16x16x32_bf16(pa[ks], as_bf16x8(wh[n][ks]), hacc[t][n], 0, 0, 0);
    }

    const size_t regbase = (size_t)BATCH*6*HWp;
    const size_t dirbase = regbase + (size_t)BATCH*14*HWp;
    const int pxw = px0 + lg*4;
    #pragma unroll
    for (int n = 0; n < 2; ++n) {
        const int o = n*16 + lr;
        float* plane;
        bool valid = (pxw < OWw);
        if (o < 6)       plane = out + ((size_t)b*6 + o)*HWp;
        else if (o < 20) plane = out + regbase + ((size_t)b*14 + (o - 6))*HWp;
        else if (o < 24) plane = out + dirbase + ((size_t)b*4 + (o - 20))*HWp;
        else valid = false;
        if (!valid) continue;
        #pragma unroll
        for (int t = 0; t < 4; ++t) {
            const int oy = oy0 + 4*w + t;
            if (oy < OHh)
                *(float4*)&plane[(size_t)oy*OWw + pxw] = *(float4*)&hacc[t][n];
        }
    }
}

extern "C" void kernel_launch(void* const* d_in, const int* in_sizes, int n_in,
                              void* d_out, int out_size, void* d_ws, size_t ws_size,
                              hipStream_t stream) {
    static const int EXPECT[24] = {13824000,96000,48000,576,64,64,64,64,36864,
                                   64,64,64,64,73728,128,128,128,128,768,6,1792,14,512,4};
    const void* din[24];
    {
        bool used[24] = {false};
        int perm[24];
        bool ok = (n_in >= 24);
        if (ok) {
            for (int j = 0; j < 24 && ok; ++j) {
                perm[j] = -1;
                for (int i = 0; i < 24; ++i)
                    if (!used[i] && in_sizes[i] == EXPECT[j]) { perm[j] = i; used[i] = true; break; }
                if (perm[j] < 0) ok = false;
            }
        }
        for (int j = 0; j < 24; ++j) din[j] = d_in[ok ? perm[j] : j];
        if (!ok) {
            sentinel_kernel<<<1, 64, 0, stream>>>((float*)d_out, 13000.0f + n_in);
            return;
        }
    }
    const int* coords = (const int*)din[1];
    float* out = (float*)d_out;

    // layout: flags 256 | wt1 73,728 | wt2 147,456 | whh 8,192 | whl 8,192 | zbuf 64 |
    //         mask (ALWAYS 4 x 32,768 -> no memsets in either path) |
    //         x1 bf16 (nb x 6,856,704) | canvas bf16 (nb x 27,426,816)
    const size_t X1B   = (size_t)HWp*64*2;          // 6,856,704
    const size_t CANB  = (size_t)NYg*NXg*64*2;      // 27,426,816
    const size_t MASKB = (size_t)MASKW*4;           // 32,768 per batch
    const size_t ZOFF  = 256 + 73728 + 147456 + 8192 + 8192;   // 237,824
    const size_t BASE  = ZOFF + 64;                 // 237,888
    const size_t NEED1 = BASE + 4*MASKB + X1B + CANB;
    const size_t NEED4 = BASE + 4*MASKB + 4*(X1B + CANB);
    if (ws_size < NEED1) {
        sentinel_kernel<<<1, 64, 0, stream>>>(out, 10000.0f + (float)(ws_size >> 20));
        return;
    }
    const int nb = (ws_size >= NEED4) ? 4 : 1;
    char* ws = (char*)d_ws;
    int* flags = (int*)ws;
    unsigned short* wt1 = (unsigned short*)(ws + 256);
    unsigned short* wt2 = (unsigned short*)(ws + 256 + 73728);
    unsigned short* whh = (unsigned short*)(ws + 256 + 73728 + 147456);
    unsigned short* whl = (unsigned short*)(ws + 256 + 73728 + 147456 + 8192);
    unsigned int*   zbuf = (unsigned int*)(ws + ZOFF);
    unsigned int*   maskbuf = (unsigned int*)(ws + BASE);
    unsigned short* x1  = (unsigned short*)(ws + BASE + 4*MASKB);
    unsigned short* canvas = (unsigned short*)(ws + BASE + 4*MASKB + (size_t)nb*X1B);

    prep_weights<<<288, 256, 0, stream>>>(
        din[0], din[3], din[4], din[5], din[6], din[7],
        din[8], din[9], din[10], din[11], din[12],
        din[13], din[14], din[15], din[16], din[17],
        din[18], din[19], din[20], din[21], din[22], din[23],
        wt1, wt2, whh, whl, maskbuf, 4*MASKW, zbuf, flags);

    if (nb == 4) {
        pfn_scatter<<<dim3(NPIL/4, 4), 256, 0, stream>>>(
            din[0], coords, din[3], din[4], din[5], din[6], din[7], flags, 0, maskbuf, canvas);
        conv1_mfma<<<dim3(14, 16, 4), 256, 0, stream>>>(
            canvas, maskbuf, wt1, (const uint4*)zbuf,
            din[9], din[10], din[11], din[12], flags, x1);
        conv2_mfma<<<dim3(14, 16, 4), 256, 0, stream>>>(
            x1, wt2, whh, whl, (const uint4*)zbuf, din[14], din[15], din[16], din[17],
            din[19], din[21], din[23], flags, 0, out);
    } else {
        for (int b = 0; b < BATCH; ++b) {
            unsigned int* mb = maskbuf + (size_t)b * MASKW;   // per-batch mask, pre-zeroed
            pfn_scatter<<<dim3(NPIL/4, 1), 256, 0, stream>>>(
                din[0], coords, din[3], din[4], din[5], din[6], din[7], flags, b, mb, canvas);
            conv1_mfma<<<dim3(14, 16, 1), 256, 0, stream>>>(
                canvas, mb, wt1, (const uint4*)zbuf,
                din[9], din[10], din[11], din[12], flags, x1);
            conv2_mfma<<<dim3(14, 16, 1), 256, 0, stream>>>(
                x1, wt2, whh, whl, (const uint4*)zbuf, din[14], din[15], din[16], din[17],
                din[19], din[21], din[23], flags, b, out);
        }
    }
}

// Round 14
// 298.233 us; speedup vs baseline: 1.1882x; 1.0312x over previous
//
#include <hip/hip_runtime.h>

// ---------------- constants ----------------
#define BATCH 4
#define NPIL 12000
#define NPTS 32
#define NCH 9
#define NXg 432
#define NYg 496
#define OHh 248
#define OWw 216
#define HWp (OHh*OWw)          // 53568
#define CAN_STRIDE ((size_t)NYg*NXg*64)      // ushort elems (bf16 canvas)
#define X1_STRIDE  ((size_t)OHh*OWw*64)      // ushort elems (bf16 x1)
#define MASKW 8192                            // mask words per batch (padded)

typedef __bf16 bf16x8 __attribute__((ext_vector_type(8)));
typedef float  f32x4  __attribute__((ext_vector_type(4)));

__device__ __forceinline__ bf16x8 as_bf16x8(uint4 u) {
    union { uint4 u; bf16x8 b; } c; c.u = u; return c.b;
}

__device__ __forceinline__ float b2f(unsigned int u) {
    union { unsigned int i; float f; } x; x.i = (u & 0xffffu) << 16; return x.f;
}
__device__ __forceinline__ unsigned short f2b(float f) {
    union { float f; unsigned int i; } x; x.f = f;
    unsigned int r = x.i + 0x7fffu + ((x.i >> 16) & 1u);   // RNE
    return (unsigned short)(r >> 16);
}
__device__ __forceinline__ float ldin(const void* p, int i, int isbf) {
    return isbf ? b2f(((const unsigned short*)p)[i]) : ((const float*)p)[i];
}

// async global->LDS DMA, 16B per lane. LDS dest must be (wave-uniform base + lane*16);
// global source may be fully per-lane (m173 pattern: swizzle lives on the SOURCE address).
__device__ __forceinline__ void async_load16(const void* gsrc, void* ldst) {
    __builtin_amdgcn_global_load_lds(
        (const __attribute__((address_space(1))) unsigned char*)gsrc,
        (__attribute__((address_space(3))) unsigned char*)ldst, 16, 0, 0);
}

__global__ void sentinel_kernel(float* out, float val) {
    if (threadIdx.x == 0) out[0] = val;
}

// ---------------- dtype plausibility (robustness; all fp32 in practice) ----------------
__device__ __forceinline__ int plaus16(unsigned short h) {
    if ((h & 0x7fffu) == 0) return 1;
    unsigned e = (h >> 7) & 0xffu;
    return (e >= 106 && e <= 132) ? 1 : 0;
}

// ---------------- weight prep + integrated per-block dtype detection ----------------
__global__ __launch_bounds__(256) void prep_weights(
    const void* q0,  const void* q1,  const void* q2,  const void* q3,
    const void* q4,  const void* q5,  const void* q6,  const void* q7,
    const void* q8,  const void* q9,  const void* q10, const void* q11,
    const void* q12, const void* q13, const void* q14, const void* q15,
    const void* q16, const void* q17, const void* q18, const void* q19,
    const void* q20, const void* q21,
    unsigned short* __restrict__ wt1, unsigned short* __restrict__ wt2,
    unsigned short* __restrict__ whh, unsigned short* __restrict__ whl,
    unsigned int* __restrict__ mask, int mask_words,
    unsigned int* __restrict__ zbuf,
    int* __restrict__ flags_out)
{
    __shared__ int votes[22];
    __shared__ int sflags[24];
    const void* ptrs[22] = {q0,q1,q2,q3,q4,q5,q6,q7,q8,q9,q10,q11,
                            q12,q13,q14,q15,q16,q17,q18,q19,q20,q21};
    const int Ks[22]   = {64,64,32,32,32,32,64,32,32,32,32,64,64,64,64,64,64,3,64,7,64,2};
    const int didx[22] = {0,3,4,5,6,7,8,9,10,11,12,13,14,15,16,17,18,19,20,21,22,23};
    const int tid = threadIdx.x;
    if (tid < 22) votes[tid] = 0;
    if (tid < 24) sflags[tid] = 0;
    __syncthreads();
    #pragma unroll 1
    for (int wb = 0; wb < 4; ++wb) {          // 4 windows cover cumulative offset space (972)
        const int vt = wb*256 + tid;
        int off = 0;
        #pragma unroll                         // full unroll -> constant ptrs[] indices (SGPR)
        for (int t = 0; t < 22; ++t) {
            if (vt >= off && vt < off + Ks[t]) {
                unsigned w = ((const unsigned*)ptrs[t])[vt - off];
                if (plaus16((unsigned short)w) && plaus16((unsigned short)(w >> 16)))
                    atomicAdd(&votes[t], 1);
            }
            off += Ks[t];
        }
    }
    __syncthreads();
    if (tid < 22) {
        int isbf;
        if (tid == 17 || tid == 19 || tid == 21) {
            int pv = votes[17] + votes[19] + votes[21];
            isbf = (pv * 4 >= 3 * 12);
        } else {
            isbf = (votes[tid] * 4 >= 3 * Ks[tid]);
        }
        sflags[didx[tid]] = isbf;
    }
    __syncthreads();
    if (blockIdx.x == 0 && tid < 24) flags_out[tid] = sflags[tid];

    const int f1 = sflags[8], f2 = sflags[13];
    int i = blockIdx.x * 256 + tid;
    if (i < mask_words) mask[i] = 0u;
    if (i < 16) zbuf[i] = 0u;
    if (i < 64*64*9) {
        int kx = i % 3; int t = i / 3; int ky = t % 3; t /= 3; int ic = t % 64; int oc = t / 64;
        wt1[((size_t)(ky*3 + kx)*64 + oc)*64 + ic] = f2b(ldin(q6, i, f1));      // q6 = w1
    }
    if (i < 128*64*9) {
        int kx = i % 3; int t = i / 3; int ky = t % 3; t /= 3; int ic = t % 64; int oc = t / 64;
        wt2[((size_t)(ky*3 + kx)*128 + oc)*64 + ic] = f2b(ldin(q11, i, f2));    // q11 = w2
    }
    if (i < 32*128) {
        int ic = i & 127, o = i >> 7;
        float wv = 0.f;
        if (o < 6)       wv = ldin(q16, o*128 + ic, sflags[18]);                // cls_w
        else if (o < 20) wv = ldin(q18, (o-6)*128 + ic, sflags[20]);            // reg_w
        else if (o < 24) wv = ldin(q20, (o-20)*128 + ic, sflags[22]);           // dir_w
        unsigned short hi = f2b(wv);
        whh[i] = hi;
        whl[i] = f2b(wv - b2f(hi));
    }
}

// ---------------- PFN + scatter, canvas NHWC bf16 [NY,NX,64] + occupancy mask ----------------
// 16 pillars/block (4 per wave): per-wave constants (w[], s, t) amortized 4x, block count
// 12,000 -> 3,000, staging is one coalesced pass over a contiguous 18KB pillar chunk.
// LDS 24,576 B. Padded 12-float rows -> 3 aligned float4 broadcasts per point.
__global__ __launch_bounds__(256) void pfn_scatter(
    const void* __restrict__ pillars, const int* __restrict__ coords,
    const void* __restrict__ pfn_w,
    const void* __restrict__ g, const void* __restrict__ bb,
    const void* __restrict__ m, const void* __restrict__ v,
    const int* __restrict__ flags, int b0,
    unsigned int* __restrict__ mask,
    unsigned short* __restrict__ canvas)
{
    __shared__ __align__(16) float lds[16][NPTS*12];   // 24,576 B
    const int tid = threadIdx.x;
    const int wslot = tid >> 6;
    const int lane  = tid & 63;
    const int b = b0 + blockIdx.y;
    canvas += (size_t)blockIdx.y * CAN_STRIDE;
    mask   += (size_t)blockIdx.y * MASKW;
    const size_t pgbase = (size_t)b * NPIL + blockIdx.x * 16;

    if (flags[0]) {
        const unsigned short* src = (const unsigned short*)pillars + pgbase * (NPTS*NCH);
        for (int idx = tid; idx < 16*NPTS*NCH; idx += 256) {
            const int pl = idx / (NPTS*NCH), e = idx % (NPTS*NCH);
            lds[pl][(e/9)*12 + e%9] = b2f(src[idx]);
        }
    } else {
        const float4* src = (const float4*)((const float*)pillars + pgbase * (NPTS*NCH));
        for (int i = tid; i < 16*(NPTS*NCH)/4; i += 256) {   // 288%4==0 -> float4 stays in-pillar
            float4 d = src[i];
            const int pl = i / 72;
            const int e0 = (i % 72) * 4;
            lds[pl][((e0    )/9)*12 + (e0    )%9] = d.x;
            lds[pl][((e0 + 1)/9)*12 + (e0 + 1)%9] = d.y;
            lds[pl][((e0 + 2)/9)*12 + (e0 + 2)%9] = d.z;
            lds[pl][((e0 + 3)/9)*12 + (e0 + 3)%9] = d.w;
        }
    }
    float w[NCH];
    const int fW = flags[3];
    #pragma unroll
    for (int c = 0; c < NCH; ++c) w[c] = ldin(pfn_w, lane*NCH + c, fW);
    float s = ldin(g, lane, flags[4]) / sqrtf(ldin(v, lane, flags[7]) + 1e-5f);
    float t = ldin(bb, lane, flags[5]) - ldin(m, lane, flags[6]) * s;
    __syncthreads();

    #pragma unroll 1
    for (int k = 0; k < 4; ++k) {
        const int pl = wslot*4 + k;
        float mx = 0.0f;
        #pragma unroll 4
        for (int n = 0; n < NPTS; ++n) {
            const float4* r4 = (const float4*)&lds[pl][n*12];
            float4 a0 = r4[0], a1 = r4[1], a2 = r4[2];
            float acc = a0.x * w[0];
            acc = fmaf(a0.y, w[1], acc);
            acc = fmaf(a0.z, w[2], acc);
            acc = fmaf(a0.w, w[3], acc);
            acc = fmaf(a1.x, w[4], acc);
            acc = fmaf(a1.y, w[5], acc);
            acc = fmaf(a1.z, w[6], acc);
            acc = fmaf(a1.w, w[7], acc);
            acc = fmaf(a2.x, w[8], acc);
            mx = fmaxf(mx, fmaxf(fmaf(acc, s, t), 0.0f));
        }
        const size_t pg = pgbase + pl;
        const int cx = coords[pg*2], cy = coords[pg*2 + 1];
        if (cx + cy != 0 && cx >= 0 && cx < NXg && cy >= 0 && cy < NYg) {
            const int cell = cy*NXg + cx;
            canvas[(size_t)cell*64 + lane] = f2b(mx);
            if (lane == 0) atomicOr(&mask[cell >> 5], 1u << (cell & 31));
        }
    }
}

// B-fragment loader for conv1 (direct from L2-resident wt1)
#define LDB1(buf, tap, ks) { \
    _Pragma("unroll") \
    for (int j_ = 0; j_ < 4; ++j_) \
        buf[j_] = *(const uint4*)&wt[((size_t)((tap)*64 + j_*16 + lr))*64 + (ks)*32 + lg*8]; \
}

// ---------------- conv1 (MFMA): canvas bf16 -> x1 bf16 [248,216,64], stride 2 ----------------
// r13-exact: odd/even row-sharing + per-phase mask-word precache in LDS.
__global__ __launch_bounds__(256, 2) void conv1_mfma(
    const unsigned short* __restrict__ canvas,
    const unsigned int* __restrict__ mask,
    const unsigned short* __restrict__ wt,     // bf16 [9][64 oc][64 ic]
    const uint4* __restrict__ zbuf,
    const void* __restrict__ g, const void* __restrict__ bb,
    const void* __restrict__ m, const void* __restrict__ v,
    const int* __restrict__ flags,
    unsigned short* __restrict__ x1)
{
    __shared__ __align__(16) uint4 lin[17*33*8];   // 71,808 B
    __shared__ int smask[17*4];                    // {3 words, base} per halo row (+272 B)
    const int tid = threadIdx.x;
    const int w = tid >> 6, l = tid & 63;
    const int lr = l & 15, lg = l >> 4;
    const int px0 = blockIdx.x * 16, oy0 = blockIdx.y * 16;
    canvas += (size_t)blockIdx.z * CAN_STRIDE;
    mask   += (size_t)blockIdx.z * MASKW;
    x1     += (size_t)blockIdx.z * X1_STRIDE;

    const int gxb = (2*px0 - 1 < 0) ? 0 : 2*px0 - 1;   // clamped halo start (for word base)

    f32x4 acc[4][4];
    #pragma unroll
    for (int t = 0; t < 4; ++t)
        #pragma unroll
        for (int n = 0; n < 4; ++n) acc[t][n] = (f32x4){0.f,0.f,0.f,0.f};

    uint4 wbA[4], wbB[4];
    // phase-A tap order: (0,0),(2,0),(0,1),(2,1),(0,2),(2,2) -> taps {0,6,1,7,2,8}
    LDB1(wbA, 0, 0);

    // ---- phase A: precache mask rows, stage 17 odd rows (iy = 2*oy0 - 1 + 2j) ----
    if (tid < 17*3) {
        const int j = tid / 3, wo = tid % 3;
        const int iy = 2*oy0 - 1 + 2*j;
        const int bw = (iy*NXg + gxb) >> 5;
        unsigned wv = 0u;
        if ((unsigned)iy < (unsigned)NYg) wv = mask[bw + wo];
        smask[j*4 + wo] = (int)wv;
        if (wo == 0) smask[j*4 + 3] = bw;
    }
    __syncthreads();
    for (int q = tid; q < 17*33*8; q += 256) {
        int s = q & 7, t2 = q >> 3, c = t2 % 33, j = t2 / 33;
        int iy = 2*oy0 - 1 + 2*j, gx = 2*px0 - 1 + c;
        const void* src = zbuf;
        if ((unsigned)iy < (unsigned)NYg && (unsigned)gx < (unsigned)NXg) {
            const int cell = iy*NXg + gx;
            const int wr = (cell >> 5) - smask[j*4 + 3];
            if ((smask[j*4 + wr] >> (cell & 31)) & 1)
                src = &canvas[(size_t)cell*64 + (s ^ ((c >> 1) & 7))*8];
        }
        async_load16(src, &lin[q]);
    }
    __syncthreads();                           // drains DMA
    {
        const int SEQA[6] = {0, 6, 1, 7, 2, 8};
        #pragma unroll
        for (int i = 0; i < 6; ++i) {
            const int tap = SEQA[i];
            const int kx = tap % 3;
            const int joff = (tap >= 6) ? 1 : 0;   // ky=2 reads odd row j=m+1
            const int c = 2*lr + kx;
            const int key = (c >> 1) & 7;
            LDB1(wbB, tap, 1);
            __builtin_amdgcn_s_setprio(1);
            #pragma unroll
            for (int t = 0; t < 4; ++t) {
                const int base = ((4*w + t + joff)*33 + c)*8;
                bf16x8 a0 = as_bf16x8(lin[base + (lg ^ key)]);
                #pragma unroll
                for (int n = 0; n < 4; ++n)
                    acc[t][n] = __builtin_amdgcn_mfma_f32_16x16x32_bf16(a0, as_bf16x8(wbA[n]), acc[t][n], 0, 0, 0);
            }
            __builtin_amdgcn_s_setprio(0);
            LDB1(wbA, (i < 5) ? SEQA[i + 1] : 3, 0);   // i=5 prefetches phase-B tap 3
            __builtin_amdgcn_s_setprio(1);
            #pragma unroll
            for (int t = 0; t < 4; ++t) {
                const int base = ((4*w + t + joff)*33 + c)*8;
                bf16x8 a1 = as_bf16x8(lin[base + ((4 + lg) ^ key)]);
                #pragma unroll
                for (int n = 0; n < 4; ++n)
                    acc[t][n] = __builtin_amdgcn_mfma_f32_16x16x32_bf16(a1, as_bf16x8(wbB[n]), acc[t][n], 0, 0, 0);
            }
            __builtin_amdgcn_s_setprio(0);
        }
    }

    // ---- phase B: precache, stage 16 even rows (iy = 2*oy0 + 2j), compute ky=1 ----
    __syncthreads();                           // drain phase-A readers
    if (tid < 16*3) {
        const int j = tid / 3, wo = tid % 3;
        const int iy = 2*oy0 + 2*j;
        const int bw = (iy*NXg + gxb) >> 5;
        unsigned wv = 0u;
        if ((unsigned)iy < (unsigned)NYg) wv = mask[bw + wo];
        smask[j*4 + wo] = (int)wv;
        if (wo == 0) smask[j*4 + 3] = bw;
    }
    __syncthreads();
    for (int q = tid; q < 16*33*8; q += 256) {
        int s = q & 7, t2 = q >> 3, c = t2 % 33, j = t2 / 33;
        int iy = 2*oy0 + 2*j, gx = 2*px0 - 1 + c;
        const void* src = zbuf;
        if ((unsigned)iy < (unsigned)NYg && (unsigned)gx < (unsigned)NXg) {
            const int cell = iy*NXg + gx;
            const int wr = (cell >> 5) - smask[j*4 + 3];
            if ((smask[j*4 + wr] >> (cell & 31)) & 1)
                src = &canvas[(size_t)cell*64 + (s ^ ((c >> 1) & 7))*8];
        }
        async_load16(src, &lin[q]);
    }
    __syncthreads();
    #pragma unroll
    for (int tap = 3; tap < 6; ++tap) {        // ky=1, kx = tap-3
        const int kx = tap - 3;
        const int c = 2*lr + kx;
        const int key = (c >> 1) & 7;
        LDB1(wbB, tap, 1);
        __builtin_amdgcn_s_setprio(1);
        #pragma unroll
        for (int t = 0; t < 4; ++t) {
            const int base = ((4*w + t)*33 + c)*8;
            bf16x8 a0 = as_bf16x8(lin[base + (lg ^ key)]);
            #pragma unroll
            for (int n = 0; n < 4; ++n)
                acc[t][n] = __builtin_amdgcn_mfma_f32_16x16x32_bf16(a0, as_bf16x8(wbA[n]), acc[t][n], 0, 0, 0);
        }
        __builtin_amdgcn_s_setprio(0);
        if (tap < 5) LDB1(wbA, tap + 1, 0);
        __builtin_amdgcn_s_setprio(1);
        #pragma unroll
        for (int t = 0; t < 4; ++t) {
            const int base = ((4*w + t)*33 + c)*8;
            bf16x8 a1 = as_bf16x8(lin[base + ((4 + lg) ^ key)]);
            #pragma unroll
            for (int n = 0; n < 4; ++n)
                acc[t][n] = __builtin_amdgcn_mfma_f32_16x16x32_bf16(a1, as_bf16x8(wbB[n]), acc[t][n], 0, 0, 0);
        }
        __builtin_amdgcn_s_setprio(0);
    }

    float s[4], tt[4];
    #pragma unroll
    for (int n = 0; n < 4; ++n) {
        const int oc = n*16 + lr;
        s[n]  = ldin(g, oc, flags[9]) / sqrtf(ldin(v, oc, flags[12]) + 1e-5f);
        tt[n] = ldin(bb, oc, flags[10]) - ldin(m, oc, flags[11]) * s[n];
    }
    // D: col = lr = oc, row = lg*4+r = px
    #pragma unroll
    for (int t = 0; t < 4; ++t) {
        const int oy = oy0 + 4*w + t;
        if (oy >= OHh) continue;
        #pragma unroll
        for (int r = 0; r < 4; ++r) {
            const int px = px0 + lg*4 + r;
            if (px >= OWw) continue;
            unsigned short* orow = &x1[((size_t)oy*OWw + px)*64 + lr];
            #pragma unroll
            for (int n = 0; n < 4; ++n)
                orow[n*16] = f2b(fmaxf(fmaf(acc[t][n][r], s[n], tt[n]), 0.f));
        }
    }
}

// ---------------- conv2 (MFMA) + fused heads — r8..r13-exact ----------------
__global__ __launch_bounds__(256, 2) void conv2_mfma(
    const unsigned short* __restrict__ x1,
    const unsigned short* __restrict__ wt,     // bf16 [9][128 oc][64 ic]
    const unsigned short* __restrict__ whh,    // bf16 [32 o][128 ic] head W hi
    const unsigned short* __restrict__ whl,    // bf16 [32 o][128 ic] head W lo
    const uint4* __restrict__ zbuf,
    const void* __restrict__ g, const void* __restrict__ bb,
    const void* __restrict__ m, const void* __restrict__ v,
    const void* __restrict__ cls_b, const void* __restrict__ reg_b, const void* __restrict__ dir_b,
    const int* __restrict__ flags, int b0,
    float* __restrict__ out)
{
    __shared__ __align__(16) char smem[74240];     // lin 41,472 | lw 32,768 ; P overlays 65,536
    uint4* lin = (uint4*)smem;
    uint4 (*lw)[128*8] = (uint4 (*)[128*8])(smem + 41472);
    unsigned short* P = (unsigned short*)smem;

    const int tid = threadIdx.x;
    const int w = tid >> 6, l = tid & 63;
    const int lr = l & 15, lg = l >> 4;
    const int px0 = blockIdx.x * 16, oy0 = blockIdx.y * 16;
    const int b = b0 + blockIdx.z;
    x1 += (size_t)blockIdx.z * X1_STRIDE;

    // stage lin via DMA (zero-stub for halo OOB)
    for (int q = tid; q < 18*18*8; q += 256) {
        int s = q & 7, t2 = q >> 3, c = t2 % 18, r = t2 / 18;
        int iy = oy0 - 1 + r, gx = px0 - 1 + c;
        const void* src = zbuf;
        if ((unsigned)iy < (unsigned)OHh && (unsigned)gx < (unsigned)OWw)
            src = &x1[((size_t)(iy*OWw + gx))*64 + (s ^ (c & 7))*8];
        async_load16(src, &lin[q]);
    }
    // stage lw[0] (tap 0) via DMA
    #pragma unroll
    for (int i = 0; i < 4; ++i) {
        const int q = tid + i*256, oc = q >> 3, s = q & 7;
        async_load16(&wt[((size_t)oc)*64 + (s ^ (oc & 7))*8], &lw[0][q]);
    }
    __syncthreads();

    f32x4 acc[4][8];
    #pragma unroll
    for (int t = 0; t < 4; ++t)
        #pragma unroll
        for (int n = 0; n < 8; ++n) acc[t][n] = (f32x4){0.f,0.f,0.f,0.f};

    #pragma unroll 1
    for (int tap = 0; tap < 9; ++tap) {
        const int ky = tap / 3, kx = tap - 3*ky;
        const int cur = tap & 1;
        if (tap < 8) {                          // DMA next tap's weights into the other buffer
            #pragma unroll
            for (int i = 0; i < 4; ++i) {
                const int q = tid + i*256, oc = q >> 3, s = q & 7;
                async_load16(&wt[((size_t)((tap+1)*128 + oc))*64 + (s ^ (oc & 7))*8],
                             &lw[cur ^ 1][q]);
            }
        }
        const int c = lr + kx;
        const int key = c & 7;
        bf16x8 af[4][2];
        #pragma unroll
        for (int t = 0; t < 4; ++t) {
            const int base = ((4*w + t + ky)*18 + c)*8;
            af[t][0] = as_bf16x8(lin[base + (lg ^ key)]);
            af[t][1] = as_bf16x8(lin[base + ((4 + lg) ^ key)]);
        }
        __builtin_amdgcn_s_setprio(1);
        #pragma unroll
        for (int n = 0; n < 8; ++n) {
            const int oc = n*16 + lr;
            const bf16x8 b0 = as_bf16x8(lw[cur][oc*8 + (lg ^ (oc & 7))]);
            const bf16x8 b1 = as_bf16x8(lw[cur][oc*8 + ((4 + lg) ^ (oc & 7))]);
            #pragma unroll
            for (int t = 0; t < 4; ++t) {
                acc[t][n] = __builtin_amdgcn_mfma_f32_16x16x32_bf16(af[t][0], b0, acc[t][n], 0, 0, 0);
                acc[t][n] = __builtin_amdgcn_mfma_f32_16x16x32_bf16(af[t][1], b1, acc[t][n], 0, 0, 0);
            }
        }
        __builtin_amdgcn_s_setprio(0);
        __syncthreads();                        // drains DMA; next tap's lw ready
    }

    float s[8], tt[8];
    #pragma unroll
    for (int n = 0; n < 8; ++n) {
        const int oc = n*16 + lr;
        s[n]  = ldin(g, oc, flags[14]) / sqrtf(ldin(v, oc, flags[17]) + 1e-5f);
        tt[n] = ldin(bb, oc, flags[15]) - ldin(m, oc, flags[16]) * s[n];
    }

    // ---- fused heads (r2-exact epilogue: pre-held hi/lo weights) ----
    float bias0, bias1;
    {
        int o = lr;
        bias0 = (o < 6) ? ldin(cls_b, o, flags[19]) : ldin(reg_b, o - 6, flags[21]);
        o = 16 + lr;
        bias1 = (o < 20) ? ldin(reg_b, o - 6, flags[21])
              : (o < 24) ? ldin(dir_b, o - 20, flags[23]) : 0.f;
    }
    uint4 wh[2][4], wl[2][4];
    #pragma unroll
    for (int n = 0; n < 2; ++n)
        #pragma unroll
        for (int ks = 0; ks < 4; ++ks) {
            const int ei = (n*16 + lr)*128 + ks*32 + lg*8;
            wh[n][ks] = *(const uint4*)&whh[ei];
            wl[n][ks] = *(const uint4*)&whl[ei];
        }

    __syncthreads();            // all waves done reading lin/lw before P overlay
    #pragma unroll
    for (int t = 0; t < 4; ++t) {
        const int pb = ((4*w + t)*16 + lg*4) * 128;
        #pragma unroll
        for (int n = 0; n < 8; ++n) {
            const int kk = 2*n + (lr >> 3), wi = lr & 7;
            #pragma unroll
            for (int r = 0; r < 4; ++r) {
                float val = fmaxf(fmaf(acc[t][n][r], s[n], tt[n]), 0.f);
                unsigned short h = f2b(val);
                P[pb + r*128 + ((kk ^ (lg*4 + r)) << 3) + wi] = h;
                acc[t][n][r] = val - b2f(h);
            }
        }
    }
    __syncthreads();

    f32x4 hacc[4][2];
    #pragma unroll
    for (int t = 0; t < 4; ++t) {
        hacc[t][0] = (f32x4){bias0, bias0, bias0, bias0};
        hacc[t][1] = (f32x4){bias1, bias1, bias1, bias1};
    }
    // pass 1: hi*Whi + hi*Wlo
    #pragma unroll
    for (int t = 0; t < 4; ++t) {
        const int mt = 4*w + t;
        bf16x8 pa[4];
        #pragma unroll
        for (int ks = 0; ks < 4; ++ks)
            pa[ks] = as_bf16x8(((const uint4*)P)[(mt*16 + lr)*16 + ((ks*4 + lg) ^ lr)]);
        #pragma unroll
        for (int n = 0; n < 2; ++n)
            #pragma unroll
            for (int ks = 0; ks < 4; ++ks) {
                hacc[t][n] = __builtin_amdgcn_mfma_f32_16x16x32_bf16(pa[ks], as_bf16x8(wh[n][ks]), hacc[t][n], 0, 0, 0);
                hacc[t][n] = __builtin_amdgcn_mfma_f32_16x16x32_bf16(pa[ks], as_bf16x8(wl[n][ks]), hacc[t][n], 0, 0, 0);
            }
    }
    __syncthreads();
    // fill P with lo
    #pragma unroll
    for (int t = 0; t < 4; ++t) {
        const int pb = ((4*w + t)*16 + lg*4) * 128;
        #pragma unroll
        for (int n = 0; n < 8; ++n) {
            const int kk = 2*n + (lr >> 3), wi = lr & 7;
            #pragma unroll
            for (int r = 0; r < 4; ++r)
                P[pb + r*128 + ((kk ^ (lg*4 + r)) << 3) + wi] = f2b(acc[t][n][r]);
        }
    }
    __syncthreads();
    // pass 2: lo*Whi
    #pragma unroll
    for (int t = 0; t < 4; ++t) {
        const int mt = 4*w + t;
        bf16x8 pa[4];
        #pragma unroll
        for (int ks = 0; ks < 4; ++ks)
            pa[ks] = as_bf16x8(((const uint4*)P)[(mt*16 + lr)*16 + ((ks*4 + lg) ^ lr)]);
        #pragma unroll
        for (int n = 0; n < 2; ++n)
            #pragma unroll
            for (int ks = 0; ks < 4; ++ks)
                hacc[t][n] = __builtin_amdgcn_mfma_f32_16x16x32_bf16(pa[ks], as_bf16x8(wh[n][ks]), hacc[t][n], 0, 0, 0);
    }

    const size_t regbase = (size_t)BATCH*6*HWp;
    const size_t dirbase = regbase + (size_t)BATCH*14*HWp;
    const int pxw = px0 + lg*4;
    #pragma unroll
    for (int n = 0; n < 2; ++n) {
        const int o = n*16 + lr;
        float* plane;
        bool valid = (pxw < OWw);
        if (o < 6)       plane = out + ((size_t)b*6 + o)*HWp;
        else if (o < 20) plane = out + regbase + ((size_t)b*14 + (o - 6))*HWp;
        else if (o < 24) plane = out + dirbase + ((size_t)b*4 + (o - 20))*HWp;
        else valid = false;
        if (!valid) continue;
        #pragma unroll
        for (int t = 0; t < 4; ++t) {
            const int oy = oy0 + 4*w + t;
            if (oy < OHh)
                *(float4*)&plane[(size_t)oy*OWw + pxw] = *(float4*)&hacc[t][n];
        }
    }
}

extern "C" void kernel_launch(void* const* d_in, const int* in_sizes, int n_in,
                              void* d_out, int out_size, void* d_ws, size_t ws_size,
                              hipStream_t stream) {
    static const int EXPECT[24] = {13824000,96000,48000,576,64,64,64,64,36864,
                                   64,64,64,64,73728,128,128,128,128,768,6,1792,14,512,4};
    const void* din[24];
    {
        bool used[24] = {false};
        int perm[24];
        bool ok = (n_in >= 24);
        if (ok) {
            for (int j = 0; j < 24 && ok; ++j) {
                perm[j] = -1;
                for (int i = 0; i < 24; ++i)
                    if (!used[i] && in_sizes[i] == EXPECT[j]) { perm[j] = i; used[i] = true; break; }
                if (perm[j] < 0) ok = false;
            }
        }
        for (int j = 0; j < 24; ++j) din[j] = d_in[ok ? perm[j] : j];
        if (!ok) {
            sentinel_kernel<<<1, 64, 0, stream>>>((float*)d_out, 13000.0f + n_in);
            return;
        }
    }
    const int* coords = (const int*)din[1];
    float* out = (float*)d_out;

    // layout: flags 256 | wt1 73,728 | wt2 147,456 | whh 8,192 | whl 8,192 | zbuf 64 |
    //         mask (ALWAYS 4 x 32,768 -> no memsets in either path) |
    //         x1 bf16 (nb x 6,856,704) | canvas bf16 (nb x 27,426,816)
    const size_t X1B   = (size_t)HWp*64*2;          // 6,856,704
    const size_t CANB  = (size_t)NYg*NXg*64*2;      // 27,426,816
    const size_t MASKB = (size_t)MASKW*4;           // 32,768 per batch
    const size_t ZOFF  = 256 + 73728 + 147456 + 8192 + 8192;   // 237,824
    const size_t BASE  = ZOFF + 64;                 // 237,888
    const size_t NEED1 = BASE + 4*MASKB + X1B + CANB;
    const size_t NEED4 = BASE + 4*MASKB + 4*(X1B + CANB);
    if (ws_size < NEED1) {
        sentinel_kernel<<<1, 64, 0, stream>>>(out, 10000.0f + (float)(ws_size >> 20));
        return;
    }
    const int nb = (ws_size >= NEED4) ? 4 : 1;
    char* ws = (char*)d_ws;
    int* flags = (int*)ws;
    unsigned short* wt1 = (unsigned short*)(ws + 256);
    unsigned short* wt2 = (unsigned short*)(ws + 256 + 73728);
    unsigned short* whh = (unsigned short*)(ws + 256 + 73728 + 147456);
    unsigned short* whl = (unsigned short*)(ws + 256 + 73728 + 147456 + 8192);
    unsigned int*   zbuf = (unsigned int*)(ws + ZOFF);
    unsigned int*   maskbuf = (unsigned int*)(ws + BASE);
    unsigned short* x1  = (unsigned short*)(ws + BASE + 4*MASKB);
    unsigned short* canvas = (unsigned short*)(ws + BASE + 4*MASKB + (size_t)nb*X1B);

    prep_weights<<<288, 256, 0, stream>>>(
        din[0], din[3], din[4], din[5], din[6], din[7],
        din[8], din[9], din[10], din[11], din[12],
        din[13], din[14], din[15], din[16], din[17],
        din[18], din[19], din[20], din[21], din[22], din[23],
        wt1, wt2, whh, whl, maskbuf, 4*MASKW, zbuf, flags);

    if (nb == 4) {
        pfn_scatter<<<dim3(NPIL/16, 4), 256, 0, stream>>>(
            din[0], coords, din[3], din[4], din[5], din[6], din[7], flags, 0, maskbuf, canvas);
        conv1_mfma<<<dim3(14, 16, 4), 256, 0, stream>>>(
            canvas, maskbuf, wt1, (const uint4*)zbuf,
            din[9], din[10], din[11], din[12], flags, x1);
        conv2_mfma<<<dim3(14, 16, 4), 256, 0, stream>>>(
            x1, wt2, whh, whl, (const uint4*)zbuf, din[14], din[15], din[16], din[17],
            din[19], din[21], din[23], flags, 0, out);
    } else {
        for (int b = 0; b < BATCH; ++b) {
            unsigned int* mb = maskbuf + (size_t)b * MASKW;   // per-batch mask, pre-zeroed
            pfn_scatter<<<dim3(NPIL/16, 1), 256, 0, stream>>>(
                din[0], coords, din[3], din[4], din[5], din[6], din[7], flags, b, mb, canvas);
            conv1_mfma<<<dim3(14, 16, 1), 256, 0, stream>>>(
                canvas, mb, wt1, (const uint4*)zbuf,
                din[9], din[10], din[11], din[12], flags, x1);
            conv2_mfma<<<dim3(14, 16, 1), 256, 0, stream>>>(
                x1, wt2, whh, whl, (const uint4*)zbuf, din[14], din[15], din[16], din[17],
                din[19], din[21], din[23], flags, b, out);
        }
    }
}